// Round 6
// baseline (1743.701 us; speedup 1.0000x reference)
//
#include <hip/hip_runtime.h>
#include <math.h>

#define OBS 8
#define SEQL 12
#define G 96
#define PP 16
#define B 1536
#define HD 128
#define ED 64
#define BOT 1024
#define MIDD 512
#define CTXD (HD + BOT)   /* 1152 */
#define MLPH 1024

typedef __attribute__((ext_vector_type(8))) short bf16x8;
typedef __attribute__((ext_vector_type(4))) float f32x4;

__device__ inline short f2bf(float x) {
    union { float f; unsigned u; } v; v.f = x;
    unsigned r = v.u + 0x7fffu + ((v.u >> 16) & 1u);   // RNE
    return (short)(r >> 16);
}

// ---------------------------------------------------------------------------
// setup kernels
// ---------------------------------------------------------------------------
// B-matrix -> MFMA-fragment-order bf16. src is (Nrows x Kcols) row-major fp32.
// dst unit u = (kt*NT + nt)*64 + lane: B[n=nt*16+(l&15)][k=kt*32+((l>>4)<<3)+e]
__global__ void swizzleB_kernel(const float* __restrict__ src, unsigned short* __restrict__ dst,
                                int NT, int K, int total) {
    int u = blockIdx.x * 256 + threadIdx.x;
    if (u >= total) return;
    int l = u & 63; int v = u >> 6; int nt = v % NT; int kt = v / NT;
    int n = nt * 16 + (l & 15);
    int k = kt * 32 + ((l >> 4) << 3);
    const float* s = src + n * K + k;
    float4 s0 = *(const float4*)s;
    float4 s1 = *(const float4*)(s + 4);
    bf16x8 o;
    o[0] = f2bf(s0.x); o[1] = f2bf(s0.y); o[2] = f2bf(s0.z); o[3] = f2bf(s0.w);
    o[4] = f2bf(s1.x); o[5] = f2bf(s1.y); o[6] = f2bf(s1.z); o[7] = f2bf(s1.w);
    *(bf16x8*)(dst + u * 8) = o;
}

// gates B = [W_ih | W_hh] (512 x 192) -> frag order (6 kt x 32 nt)
__global__ void swizzle_cat_kernel(const float* __restrict__ W_ih, const float* __restrict__ W_hh,
                                   unsigned short* __restrict__ dst) {
    int u = blockIdx.x * 256 + threadIdx.x;   // 6*32*64 = 12288 units
    if (u >= 6 * 32 * 64) return;
    int l = u & 63; int v = u >> 6; int nt = v & 31; int kt = v >> 5;
    int n = nt * 16 + (l & 15);
    int k0 = kt * 32 + ((l >> 4) << 3);
    bf16x8 o;
#pragma unroll
    for (int e = 0; e < 8; ++e) {
        int k = k0 + e;
        float val = (k < ED) ? W_ih[n * ED + k] : W_hh[n * HD + (k - ED)];
        o[e] = f2bf(val);
    }
    *(bf16x8*)(dst + u * 8) = o;
}

// Ab B-matrix = [Wp1_h | M0 | M1 | CV | 0pad] (512 x 160) -> frag order (5 kt x 32 nt)
__global__ void swizzle_p1_kernel(const float* __restrict__ Wp1, const float* __restrict__ M0,
                                  const float* __restrict__ M1, const float* __restrict__ CV,
                                  unsigned short* __restrict__ dst) {
    int u = blockIdx.x * 256 + threadIdx.x;   // 5*32*64 = 10240 units
    if (u >= 5 * 32 * 64) return;
    int l = u & 63; int v = u >> 6; int nt = v & 31; int kt = v >> 5;
    int n = nt * 16 + (l & 15);
    int k0 = kt * 32 + ((l >> 4) << 3);
    bf16x8 o;
#pragma unroll
    for (int e = 0; e < 8; ++e) {
        int k = k0 + e;
        float val;
        if (k < HD)       val = Wp1[n * (ED + HD) + ED + k];
        else if (k == HD)     val = M0[n];
        else if (k == HD + 1) val = M1[n];
        else if (k == HD + 2) val = CV[n];
        else                  val = 0.f;
        o[e] = f2bf(val);
    }
    *(bf16x8*)(dst + u * 8) = o;
}

// M = Wp1[:, :64] @ Wp_emb  (512x2), cvec = Wp1[:, :64] @ bp_emb + bp1
__global__ void mcvec_kernel(const float* __restrict__ Wp1, const float* __restrict__ Wp_emb,
                             const float* __restrict__ bp_emb, const float* __restrict__ bp1,
                             float* __restrict__ M0, float* __restrict__ M1, float* __restrict__ CV) {
    int r = blockIdx.x * blockDim.x + threadIdx.x;
    if (r >= MIDD) return;
    float m0 = 0.f, m1 = 0.f, cv = 0.f;
    for (int e = 0; e < ED; ++e) {
        float w = Wp1[r * (ED + HD) + e];
        m0 += w * Wp_emb[e * 2 + 0];
        m1 += w * Wp_emb[e * 2 + 1];
        cv += w * bp_emb[e];
    }
    M0[r] = m0; M1[r] = m1; CV[r] = cv + bp1[r];
}

__global__ void init_kernel(const float* __restrict__ obs_traj, const float* __restrict__ obs_traj_rel,
                            const float* __restrict__ h0, const float* __restrict__ c0,
                            const float* __restrict__ W_emb, const float* __restrict__ b_emb,
                            float* __restrict__ Hb, float* __restrict__ Cb,
                            float* __restrict__ POSb, float* __restrict__ DIN) {
    int b = blockIdx.x;
    int t = threadIdx.x; // 128
    Hb[b * HD + t] = h0[b * HD + t];
    Cb[b * HD + t] = c0[b * HD + t];
    if (t < 2) POSb[b * 2 + t] = obs_traj[((OBS - 1) * B + b) * 2 + t];
    if (t < ED) {
        float rx = obs_traj_rel[((OBS - 1) * B + b) * 2 + 0];
        float ry = obs_traj_rel[((OBS - 1) * B + b) * 2 + 1];
        DIN[b * ED + t] = W_emb[t * 2 + 0] * rx + W_emb[t * 2 + 1] * ry + b_emb[t];
    }
}

// ---------------------------------------------------------------------------
// fused step: gates MFMA -> LSTM cell (in-reg) -> rel_pos -> POS/DIN update ->
// Ab MFMA. Block = one scene (16 rows), 512 thr (8 waves).
// ---------------------------------------------------------------------------
__global__ __launch_bounds__(512) void step_kernel(
    const unsigned short* __restrict__ WcatF, const float* __restrict__ b_ih,
    const float* __restrict__ b_hh,
    const float* __restrict__ W_pos, const float* __restrict__ b_pos,
    const float* __restrict__ W_emb, const float* __restrict__ b_emb,
    const unsigned short* __restrict__ Wp1F2,
    float* __restrict__ Hb, float* __restrict__ Cb, float* __restrict__ POSb,
    float* __restrict__ DIN, unsigned short* __restrict__ Hbf,
    float* __restrict__ Ab, float* __restrict__ rel_out) {

    __shared__ unsigned short gf[6 * 64 * 8];    // gates A-frags, 6KB
    __shared__ unsigned short a2f[5 * 64 * 8];   // Ab A-frags, 5KB
    __shared__ float hsh[16 * HD];               // h_lstm, 8KB
    __shared__ float relsh[16][4];

    int gsc = blockIdx.x;          // scene
    int t = threadIdx.x;
    int lane = t & 63, w = t >> 6;
    int colid = lane & 15, quad = lane >> 4;

    // build gates A-frags: [din(64) | h_prev(128)], K=192 = 6 kt
    if (t < 384) {
        int kt = t >> 6;
        int j = lane & 15;
        int b = gsc * PP + j;
        int k0 = kt * 32 + ((lane >> 4) << 3);
        float4 x0, x1;
        if (k0 < ED) {
            const float4* p = (const float4*)(DIN + b * ED + k0);
            x0 = p[0]; x1 = p[1];
        } else {
            const float4* p = (const float4*)(Hb + b * HD + (k0 - ED));
            x0 = p[0]; x1 = p[1];
        }
        bf16x8 o;
        o[0] = f2bf(x0.x); o[1] = f2bf(x0.y); o[2] = f2bf(x0.z); o[3] = f2bf(x0.w);
        o[4] = f2bf(x1.x); o[5] = f2bf(x1.y); o[6] = f2bf(x1.z); o[7] = f2bf(x1.w);
        *(bf16x8*)(gf + t * 8) = o;
    }
    __syncthreads();

    // gates MFMA
    f32x4 acc[4];
#pragma unroll
    for (int gi = 0; gi < 4; ++gi) acc[gi] = (f32x4)0.f;
#pragma unroll
    for (int kt = 0; kt < 6; ++kt) {
        bf16x8 af = *(const bf16x8*)(gf + (kt * 64 + lane) * 8);
#pragma unroll
        for (int gi = 0; gi < 4; ++gi) {
            bf16x8 bfr = *(const bf16x8*)(WcatF + ((kt * 32 + gi * 8 + w) * 64 + lane) * 8);
            acc[gi] = __builtin_amdgcn_mfma_f32_16x16x32_bf16(af, bfr, acc[gi], 0, 0, 0);
        }
    }
    // LSTM cell, all four gates in-wave
    int hcol = w * 16 + colid;
    float bias[4];
#pragma unroll
    for (int gi = 0; gi < 4; ++gi) {
        int n = (gi * 8 + w) * 16 + colid;
        bias[gi] = b_ih[n] + b_hh[n];
    }
#pragma unroll
    for (int r = 0; r < 4; ++r) {
        int row = quad * 4 + r;
        int b = gsc * PP + row;
        float gI = acc[0][r] + bias[0];
        float gF = acc[1][r] + bias[1];
        float gG = acc[2][r] + bias[2];
        float gO = acc[3][r] + bias[3];
        float c = Cb[b * HD + hcol];
        float cn = (1.f / (1.f + expf(-gF))) * c + (1.f / (1.f + expf(-gI))) * tanhf(gG);
        float hn = (1.f / (1.f + expf(-gO))) * tanhf(cn);
        Cb[b * HD + hcol] = cn;
        Hbf[b * HD + hcol] = (unsigned short)f2bf(hn);
        hsh[row * HD + hcol] = hn;
    }
    __syncthreads();

    // rel_pos: 32 threads per row, shuffle reduce
    {
        int row = t >> 5, kk = t & 31;
        float r0 = 0.f, r1 = 0.f;
#pragma unroll
        for (int q = 0; q < 4; ++q) {
            int k = kk + q * 32;
            float hv = hsh[row * HD + k];
            r0 = fmaf(hv, W_pos[k], r0);
            r1 = fmaf(hv, W_pos[HD + k], r1);
        }
#pragma unroll
        for (int m = 16; m >= 1; m >>= 1) {
            r0 += __shfl_xor(r0, m, 64);
            r1 += __shfl_xor(r1, m, 64);
        }
        if (kk == 0) {
            int b = gsc * PP + row;
            r0 += b_pos[0]; r1 += b_pos[1];
            float px = POSb[b * 2 + 0] + r0;
            float py = POSb[b * 2 + 1] + r1;
            POSb[b * 2 + 0] = px; POSb[b * 2 + 1] = py;
            rel_out[b * 2 + 0] = r0; rel_out[b * 2 + 1] = r1;
            relsh[row][0] = r0; relsh[row][1] = r1; relsh[row][2] = px; relsh[row][3] = py;
        }
    }
    __syncthreads();

    // next dec_in
#pragma unroll
    for (int rep = 0; rep < 2; ++rep) {
        int idx = rep * 512 + t;
        int row = idx >> 6, e = idx & 63;
        int b = gsc * PP + row;
        DIN[b * ED + e] = W_emb[e * 2 + 0] * relsh[row][0] +
                          W_emb[e * 2 + 1] * relsh[row][1] + b_emb[e];
    }
    // Ab A-frags: [h(128) | px | py | 1 | 0pad], K=160 = 5 kt
    if (t < 320) {
        int kt = t >> 6;
        int j = lane & 15;
        int k0 = kt * 32 + ((lane >> 4) << 3);
        bf16x8 o;
#pragma unroll
        for (int e = 0; e < 8; ++e) {
            int k = k0 + e;
            float v;
            if (k < HD)            v = hsh[j * HD + k];
            else if (k == HD)      v = relsh[j][2];
            else if (k == HD + 1)  v = relsh[j][3];
            else if (k == HD + 2)  v = 1.f;
            else                   v = 0.f;
            o[e] = f2bf(v);
        }
        *(bf16x8*)(a2f + t * 8) = o;
    }
    __syncthreads();

    // Ab MFMA: wave w -> nt = w*4+q (512 cols total)
    f32x4 acc2[4];
#pragma unroll
    for (int q = 0; q < 4; ++q) acc2[q] = (f32x4)0.f;
#pragma unroll
    for (int kt = 0; kt < 5; ++kt) {
        bf16x8 af = *(const bf16x8*)(a2f + (kt * 64 + lane) * 8);
#pragma unroll
        for (int q = 0; q < 4; ++q) {
            bf16x8 bfr = *(const bf16x8*)(Wp1F2 + ((kt * 32 + w * 4 + q) * 64 + lane) * 8);
            acc2[q] = __builtin_amdgcn_mfma_f32_16x16x32_bf16(af, bfr, acc2[q], 0, 0, 0);
        }
    }
#pragma unroll
    for (int q = 0; q < 4; ++q)
#pragma unroll
        for (int r = 0; r < 4; ++r) {
            int b = gsc * PP + quad * 4 + r;
            Ab[b * MIDD + (w * 4 + q) * 16 + colid] = acc2[q][r];
        }
}

// ---------------------------------------------------------------------------
// pool v5: A-frags built ONCE per (scene, igrp8) into 128KB LDS (all 16 kt),
// then 4 column sweeps cover the full 1024 cols — zero build replication.
// grid = G*2 = 192 blocks, 512 thr (8 waves), 1 block/CU.
// Wave w: i-pair = (w>>1)*2 + {0,1}, nt-group = w&1 (8 nt); per sweep the
// block covers 8 i x 256 cols; acc = 2x8x4 = 64 regs, reset per sweep.
// ---------------------------------------------------------------------------
__global__ __launch_bounds__(512, 2) void pool_mfma5_kernel(
    const float* __restrict__ Ab, const float* __restrict__ POSb,
    const unsigned short* __restrict__ Wp2F, const float* __restrict__ bp2,
    const float* __restrict__ M0, const float* __restrict__ M1,
    unsigned short* __restrict__ POOLbf) {

    __shared__ unsigned short af_lds[8 * 16 * 64 * 8];   // 128KB: [(ii*16+kt)*64+l][8]
    __shared__ float possh[8][2];

    int bi = blockIdx.x;        // 0..191
    int g = bi >> 1;
    int igrp = bi & 1;          // which 8 i's
    int t = threadIdx.x, lane = t & 63, w = t >> 6;

    if (t < 16)
        possh[t >> 1][t & 1] = POSb[(g * PP + igrp * 8 + (t >> 1)) * 2 + (t & 1)];
    __syncthreads();

    // build ALL A-frags once: 8 ii x 16 kt x 64 lanes = 8192 units
    const float* Ag = Ab + g * (PP * MIDD);
#pragma unroll
    for (int rep = 0; rep < 16; ++rep) {
        int u = rep * 512 + t;           // 0..8191
        int ii = u >> 10;                // 0..7
        int kt = (u >> 6) & 15;          // 0..15
        int l = u & 63;
        int j = l & 15;
        int k0 = kt * 32 + ((l >> 4) << 3);
        const float4* ap = (const float4*)(Ag + j * MIDD + k0);
        float4 a0 = ap[0], a1 = ap[1];
        const float4* m0p = (const float4*)(M0 + k0);
        const float4* m1p = (const float4*)(M1 + k0);
        float4 m00 = m0p[0], m01 = m0p[1];
        float4 m10 = m1p[0], m11 = m1p[1];
        float px = possh[ii][0], py = possh[ii][1];
        bf16x8 o;
        o[0] = f2bf(fmaxf(a0.x - fmaf(m00.x, px, m10.x * py), 0.f));
        o[1] = f2bf(fmaxf(a0.y - fmaf(m00.y, px, m10.y * py), 0.f));
        o[2] = f2bf(fmaxf(a0.z - fmaf(m00.z, px, m10.z * py), 0.f));
        o[3] = f2bf(fmaxf(a0.w - fmaf(m00.w, px, m10.w * py), 0.f));
        o[4] = f2bf(fmaxf(a1.x - fmaf(m01.x, px, m11.x * py), 0.f));
        o[5] = f2bf(fmaxf(a1.y - fmaf(m01.y, px, m11.y * py), 0.f));
        o[6] = f2bf(fmaxf(a1.z - fmaf(m01.z, px, m11.z * py), 0.f));
        o[7] = f2bf(fmaxf(a1.w - fmaf(m01.w, px, m11.w * py), 0.f));
        *(bf16x8*)(af_lds + u * 8) = o;
    }
    __syncthreads();

    int ipair = w >> 1;           // 0..3
    int ntg = w & 1;              // 0..1
    int ii0 = ipair * 2;
    int quad = lane >> 4, colid = lane & 15;

    for (int ncg = 0; ncg < 4; ++ncg) {      // column sweeps: 256 cols each
        int ntb = ncg * 16 + ntg * 8;
        f32x4 acc[2][8];
#pragma unroll
        for (int p = 0; p < 2; ++p)
#pragma unroll
            for (int n = 0; n < 8; ++n) acc[p][n] = (f32x4)0.f;

        for (int kt = 0; kt < 16; ++kt) {
            bf16x8 af0 = *(const bf16x8*)(af_lds + (((ii0 + 0) * 16 + kt) * 64 + lane) * 8);
            bf16x8 af1 = *(const bf16x8*)(af_lds + (((ii0 + 1) * 16 + kt) * 64 + lane) * 8);
#pragma unroll
            for (int ng2 = 0; ng2 < 2; ++ng2) {
                bf16x8 bfr[4];
#pragma unroll
                for (int n = 0; n < 4; ++n)
                    bfr[n] = *(const bf16x8*)(Wp2F + ((kt * 64 + ntb + ng2 * 4 + n) * 64 + lane) * 8);
#pragma unroll
                for (int n = 0; n < 4; ++n) {
                    acc[0][ng2 * 4 + n] =
                        __builtin_amdgcn_mfma_f32_16x16x32_bf16(af0, bfr[n], acc[0][ng2 * 4 + n], 0, 0, 0);
                    acc[1][ng2 * 4 + n] =
                        __builtin_amdgcn_mfma_f32_16x16x32_bf16(af1, bfr[n], acc[1][ng2 * 4 + n], 0, 0, 0);
                }
            }
        }
        // epilogue for this sweep: max over C-rows (j), then cross-quad shuffles
#pragma unroll
        for (int p = 0; p < 2; ++p) {
            int i = g * PP + igrp * 8 + ii0 + p;
#pragma unroll
            for (int n = 0; n < 8; ++n) {
                float m = fmaxf(fmaxf(acc[p][n][0], acc[p][n][1]),
                                fmaxf(acc[p][n][2], acc[p][n][3]));
                m = fmaxf(m, __shfl_xor(m, 16, 64));
                m = fmaxf(m, __shfl_xor(m, 32, 64));
                if (quad == 0) {
                    int col = (ntb + n) * 16 + colid;
                    float v = fmaxf(m + bp2[col], 0.f);
                    POOLbf[i * BOT + col] = (unsigned short)f2bf(v);
                }
            }
        }
    }
}

// ---------------------------------------------------------------------------
// MLP1 (MFMA): [Hbf | POOLbf] (1536x1152) @ Wm1F -> relu -> Y1Mbf (1536x1024)
// ---------------------------------------------------------------------------
__global__ __launch_bounds__(256) void mlp1_mfma_kernel(
    const unsigned short* __restrict__ Hbf, const unsigned short* __restrict__ POOLbf,
    const unsigned short* __restrict__ Wm1F, const float* __restrict__ bm1,
    unsigned short* __restrict__ Y1Mbf) {

    __shared__ unsigned short a_f[16 * 64 * 8];   // 16KB
    int mg = blockIdx.x;       // 0..23
    int ng = blockIdx.y;       // 0..15
    int t = threadIdx.x, lane = t & 63, w = t >> 6;
    int rh = w >> 1, nh = w & 1;

    f32x4 acc[2][2];
#pragma unroll
    for (int a = 0; a < 2; ++a)
#pragma unroll
        for (int b = 0; b < 2; ++b) acc[a][b] = (f32x4)0.f;

    for (int c = 0; c < 9; ++c) {
        __syncthreads();
#pragma unroll
        for (int u0 = 0; u0 < 1024; u0 += 256) {
            int u = u0 + t;
            int rg = u >> 8, kt = (u >> 6) & 3, l = u & 63;
            int row = mg * 64 + rg * 16 + (l & 15);
            int kl = kt * 32 + ((l >> 4) << 3);
            const unsigned short* src = (c == 0) ? (Hbf + row * HD + kl)
                                                 : (POOLbf + row * BOT + (c - 1) * 128 + kl);
            *(bf16x8*)(a_f + u * 8) = *(const bf16x8*)src;
        }
        __syncthreads();
#pragma unroll
        for (int kt = 0; kt < 4; ++kt) {
            int ktg = c * 4 + kt;
            bf16x8 bfr[2];
#pragma unroll
            for (int j = 0; j < 2; ++j) {
                int ntg = ng * 4 + nh * 2 + j;
                bfr[j] = *(const bf16x8*)(Wm1F + ((ktg * 64 + ntg) * 64 + lane) * 8);
            }
#pragma unroll
            for (int ri = 0; ri < 2; ++ri) {
                int rg = rh * 2 + ri;
                bf16x8 af = *(const bf16x8*)(a_f + ((rg * 4 + kt) * 64 + lane) * 8);
#pragma unroll
                for (int j = 0; j < 2; ++j)
                    acc[ri][j] = __builtin_amdgcn_mfma_f32_16x16x32_bf16(af, bfr[j], acc[ri][j], 0, 0, 0);
            }
        }
    }
    int quad = lane >> 4, colid = lane & 15;
#pragma unroll
    for (int ri = 0; ri < 2; ++ri)
#pragma unroll
        for (int j = 0; j < 2; ++j) {
            int col = ng * 64 + (nh * 2 + j) * 16 + colid;
            float bb = bm1[col];
#pragma unroll
            for (int r = 0; r < 4; ++r) {
                int row = mg * 64 + (rh * 2 + ri) * 16 + quad * 4 + r;
                float v = fmaxf(acc[ri][j][r] + bb, 0.f);
                Y1Mbf[row * MLPH + col] = (unsigned short)f2bf(v);
            }
        }
}

// ---------------------------------------------------------------------------
// MLP2 (MFMA): Y1Mbf (1536x1024) @ Wm2F -> relu -> Hb fp32 (and h_out last step)
// ---------------------------------------------------------------------------
__global__ __launch_bounds__(256) void mlp2_mfma_kernel(
    const unsigned short* __restrict__ Y1Mbf, const unsigned short* __restrict__ Wm2F,
    const float* __restrict__ bm2, float* __restrict__ Hb, float* __restrict__ hout) {

    __shared__ unsigned short a_f[32 * 64 * 8];   // 32KB
    int rg = blockIdx.x;   // 0..95
    int t = threadIdx.x, lane = t & 63, w = t >> 6;

#pragma unroll
    for (int u0 = 0; u0 < 2048; u0 += 256) {
        int u = u0 + t;
        int kt = u >> 6, l = u & 63;
        int row = rg * 16 + (l & 15);
        int kl = kt * 32 + ((l >> 4) << 3);
        *(bf16x8*)(a_f + u * 8) = *(const bf16x8*)(Y1Mbf + row * MLPH + kl);
    }
    __syncthreads();

    f32x4 acc[2];
    acc[0] = (f32x4)0.f; acc[1] = (f32x4)0.f;
    for (int kt = 0; kt < 32; ++kt) {
        bf16x8 af = *(const bf16x8*)(a_f + (kt * 64 + lane) * 8);
#pragma unroll
        for (int j = 0; j < 2; ++j) {
            int ntg = w * 2 + j;
            bf16x8 bfr = *(const bf16x8*)(Wm2F + ((kt * 8 + ntg) * 64 + lane) * 8);
            acc[j] = __builtin_amdgcn_mfma_f32_16x16x32_bf16(af, bfr, acc[j], 0, 0, 0);
        }
    }
    int quad = lane >> 4, colid = lane & 15;
#pragma unroll
    for (int j = 0; j < 2; ++j) {
        int col = (w * 2 + j) * 16 + colid;
        float bb = bm2[col];
#pragma unroll
        for (int r = 0; r < 4; ++r) {
            int row = rg * 16 + quad * 4 + r;
            float v = fmaxf(acc[j][r] + bb, 0.f);
            Hb[row * HD + col] = v;
            if (hout) hout[row * HD + col] = v;
        }
    }
}

// ---------------------------------------------------------------------------
extern "C" void kernel_launch(void* const* d_in, const int* in_sizes, int n_in,
                              void* d_out, int out_size, void* d_ws, size_t ws_size,
                              hipStream_t stream) {
    const float* obs_traj     = (const float*)d_in[0];
    const float* obs_traj_rel = (const float*)d_in[1];
    const float* h0    = (const float*)d_in[3];
    const float* c0    = (const float*)d_in[4];
    const float* W_emb = (const float*)d_in[6];
    const float* b_emb = (const float*)d_in[7];
    const float* W_ih  = (const float*)d_in[8];
    const float* b_ih  = (const float*)d_in[9];
    const float* W_hh  = (const float*)d_in[10];
    const float* b_hh  = (const float*)d_in[11];
    const float* W_pos = (const float*)d_in[12];
    const float* b_pos = (const float*)d_in[13];
    const float* Wp_emb= (const float*)d_in[14];
    const float* bp_emb= (const float*)d_in[15];
    const float* Wp1   = (const float*)d_in[16];
    const float* bp1   = (const float*)d_in[17];
    const float* Wp2   = (const float*)d_in[18];
    const float* bp2   = (const float*)d_in[19];
    const float* Wm1   = (const float*)d_in[20];
    const float* bm1   = (const float*)d_in[21];
    const float* Wm2   = (const float*)d_in[22];
    const float* bm2   = (const float*)d_in[23];

    float* ws = (float*)d_ws;
    float* Hb    = ws; ws += B * HD;
    float* Cb    = ws; ws += B * HD;
    float* POSb  = ws; ws += B * 2;
    float* DIN   = ws; ws += B * ED;
    float* Ab    = ws; ws += B * MIDD;
    float* M0    = ws; ws += MIDD;
    float* M1    = ws; ws += MIDD;
    float* CV    = ws; ws += MIDD;
    unsigned short* us = (unsigned short*)ws;
    unsigned short* Hbf    = us; us += B * HD;
    unsigned short* POOLbf = us; us += B * BOT;
    unsigned short* Y1Mbf  = us; us += B * MLPH;
    unsigned short* WcatF  = us; us += 6 * 32 * 64 * 8;
    unsigned short* Wp1F2  = us; us += 5 * 32 * 64 * 8;
    unsigned short* Wp2F   = us; us += MIDD * BOT;
    unsigned short* Wm1F   = us; us += CTXD * MLPH;
    unsigned short* Wm2F   = us; us += MLPH * HD;

    float* out = (float*)d_out;
    float* rels_out = out;                 // (12,1536,2)
    float* h_out    = out + SEQL * B * 2;  // (1536,128)

    // setup
    {
        int tot = 16 * 64 * 64;   // Wp2: K=512, NT=64
        swizzleB_kernel<<<(tot + 255) / 256, 256, 0, stream>>>(Wp2, Wp2F, 64, MIDD, tot);
        tot = 36 * 64 * 64;       // Wm1: K=1152, NT=64
        swizzleB_kernel<<<(tot + 255) / 256, 256, 0, stream>>>(Wm1, Wm1F, 64, CTXD, tot);
        tot = 32 * 8 * 64;        // Wm2: K=1024, NT=8
        swizzleB_kernel<<<(tot + 255) / 256, 256, 0, stream>>>(Wm2, Wm2F, 8, MLPH, tot);
        swizzle_cat_kernel<<<(6 * 32 * 64 + 255) / 256, 256, 0, stream>>>(W_ih, W_hh, WcatF);
    }
    mcvec_kernel<<<2, 256, 0, stream>>>(Wp1, Wp_emb, bp_emb, bp1, M0, M1, CV);
    swizzle_p1_kernel<<<(5 * 32 * 64 + 255) / 256, 256, 0, stream>>>(Wp1, M0, M1, CV, Wp1F2);
    init_kernel<<<B, 128, 0, stream>>>(obs_traj, obs_traj_rel, h0, c0, W_emb, b_emb,
                                       Hb, Cb, POSb, DIN);

    for (int s = 0; s < SEQL; ++s) {
        step_kernel<<<G, 512, 0, stream>>>(
            WcatF, b_ih, b_hh, W_pos, b_pos, W_emb, b_emb, Wp1F2,
            Hb, Cb, POSb, DIN, Hbf, Ab, rels_out + s * B * 2);
        pool_mfma5_kernel<<<G * 2, 512, 0, stream>>>(Ab, POSb, Wp2F, bp2, M0, M1, POOLbf);
        mlp1_mfma_kernel<<<dim3(24, 16), 256, 0, stream>>>(Hbf, POOLbf, Wm1F, bm1, Y1Mbf);
        mlp2_mfma_kernel<<<G, 256, 0, stream>>>(Y1Mbf, Wm2F, bm2, Hb,
                                                (s == SEQL - 1) ? h_out : (float*)nullptr);
    }
}

// Round 7
// 1185.266 us; speedup vs baseline: 1.4711x; 1.4711x over previous
//
#include <hip/hip_runtime.h>
#include <math.h>

#define OBS 8
#define SEQL 12
#define G 96
#define PP 16
#define B 1536
#define HD 128
#define ED 64
#define BOT 1024
#define MIDD 512
#define CTXD (HD + BOT)   /* 1152 */
#define MLPH 1024

typedef __attribute__((ext_vector_type(8))) short bf16x8;
typedef __attribute__((ext_vector_type(4))) float f32x4;

__device__ inline short f2bf(float x) {
    union { float f; unsigned u; } v; v.f = x;
    unsigned r = v.u + 0x7fffu + ((v.u >> 16) & 1u);   // RNE
    return (short)(r >> 16);
}

// ---------------------------------------------------------------------------
// setup kernels
// ---------------------------------------------------------------------------
// B-matrix -> MFMA-fragment-order bf16. src is (Nrows x Kcols) row-major fp32.
// dst unit u = (kt*NT + nt)*64 + lane: B[n=nt*16+(l&15)][k=kt*32+((l>>4)<<3)+e]
__global__ void swizzleB_kernel(const float* __restrict__ src, unsigned short* __restrict__ dst,
                                int NT, int K, int total) {
    int u = blockIdx.x * 256 + threadIdx.x;
    if (u >= total) return;
    int l = u & 63; int v = u >> 6; int nt = v % NT; int kt = v / NT;
    int n = nt * 16 + (l & 15);
    int k = kt * 32 + ((l >> 4) << 3);
    const float* s = src + n * K + k;
    float4 s0 = *(const float4*)s;
    float4 s1 = *(const float4*)(s + 4);
    bf16x8 o;
    o[0] = f2bf(s0.x); o[1] = f2bf(s0.y); o[2] = f2bf(s0.z); o[3] = f2bf(s0.w);
    o[4] = f2bf(s1.x); o[5] = f2bf(s1.y); o[6] = f2bf(s1.z); o[7] = f2bf(s1.w);
    *(bf16x8*)(dst + u * 8) = o;
}

// gates B = [W_ih | W_hh] (512 x 192) -> frag order (6 kt x 32 nt)
__global__ void swizzle_cat_kernel(const float* __restrict__ W_ih, const float* __restrict__ W_hh,
                                   unsigned short* __restrict__ dst) {
    int u = blockIdx.x * 256 + threadIdx.x;   // 6*32*64 = 12288 units
    if (u >= 6 * 32 * 64) return;
    int l = u & 63; int v = u >> 6; int nt = v & 31; int kt = v >> 5;
    int n = nt * 16 + (l & 15);
    int k0 = kt * 32 + ((l >> 4) << 3);
    bf16x8 o;
#pragma unroll
    for (int e = 0; e < 8; ++e) {
        int k = k0 + e;
        float val = (k < ED) ? W_ih[n * ED + k] : W_hh[n * HD + (k - ED)];
        o[e] = f2bf(val);
    }
    *(bf16x8*)(dst + u * 8) = o;
}

// Ab B-matrix = [Wp1_h | M0 | M1 | CV | 0pad] (512 x 160) -> frag order (5 kt x 32 nt)
__global__ void swizzle_p1_kernel(const float* __restrict__ Wp1, const float* __restrict__ M0,
                                  const float* __restrict__ M1, const float* __restrict__ CV,
                                  unsigned short* __restrict__ dst) {
    int u = blockIdx.x * 256 + threadIdx.x;   // 5*32*64 = 10240 units
    if (u >= 5 * 32 * 64) return;
    int l = u & 63; int v = u >> 6; int nt = v & 31; int kt = v >> 5;
    int n = nt * 16 + (l & 15);
    int k0 = kt * 32 + ((l >> 4) << 3);
    bf16x8 o;
#pragma unroll
    for (int e = 0; e < 8; ++e) {
        int k = k0 + e;
        float val;
        if (k < HD)       val = Wp1[n * (ED + HD) + ED + k];
        else if (k == HD)     val = M0[n];
        else if (k == HD + 1) val = M1[n];
        else if (k == HD + 2) val = CV[n];
        else                  val = 0.f;
        o[e] = f2bf(val);
    }
    *(bf16x8*)(dst + u * 8) = o;
}

// M = Wp1[:, :64] @ Wp_emb  (512x2), cvec = Wp1[:, :64] @ bp_emb + bp1
__global__ void mcvec_kernel(const float* __restrict__ Wp1, const float* __restrict__ Wp_emb,
                             const float* __restrict__ bp_emb, const float* __restrict__ bp1,
                             float* __restrict__ M0, float* __restrict__ M1, float* __restrict__ CV) {
    int r = blockIdx.x * blockDim.x + threadIdx.x;
    if (r >= MIDD) return;
    float m0 = 0.f, m1 = 0.f, cv = 0.f;
    for (int e = 0; e < ED; ++e) {
        float w = Wp1[r * (ED + HD) + e];
        m0 += w * Wp_emb[e * 2 + 0];
        m1 += w * Wp_emb[e * 2 + 1];
        cv += w * bp_emb[e];
    }
    M0[r] = m0; M1[r] = m1; CV[r] = cv + bp1[r];
}

__global__ void init_kernel(const float* __restrict__ obs_traj, const float* __restrict__ obs_traj_rel,
                            const float* __restrict__ h0, const float* __restrict__ c0,
                            const float* __restrict__ W_emb, const float* __restrict__ b_emb,
                            float* __restrict__ Hb, float* __restrict__ Cb,
                            float* __restrict__ POSb, float* __restrict__ DIN) {
    int b = blockIdx.x;
    int t = threadIdx.x; // 128
    Hb[b * HD + t] = h0[b * HD + t];
    Cb[b * HD + t] = c0[b * HD + t];
    if (t < 2) POSb[b * 2 + t] = obs_traj[((OBS - 1) * B + b) * 2 + t];
    if (t < ED) {
        float rx = obs_traj_rel[((OBS - 1) * B + b) * 2 + 0];
        float ry = obs_traj_rel[((OBS - 1) * B + b) * 2 + 1];
        DIN[b * ED + t] = W_emb[t * 2 + 0] * rx + W_emb[t * 2 + 1] * ry + b_emb[t];
    }
}

// ---------------------------------------------------------------------------
// fused step: gates MFMA -> LSTM cell (in-reg) -> rel_pos -> POS/DIN update ->
// Ab MFMA. Block = one scene (16 rows), 512 thr (8 waves).
// ---------------------------------------------------------------------------
__global__ __launch_bounds__(512) void step_kernel(
    const unsigned short* __restrict__ WcatF, const float* __restrict__ b_ih,
    const float* __restrict__ b_hh,
    const float* __restrict__ W_pos, const float* __restrict__ b_pos,
    const float* __restrict__ W_emb, const float* __restrict__ b_emb,
    const unsigned short* __restrict__ Wp1F2,
    float* __restrict__ Hb, float* __restrict__ Cb, float* __restrict__ POSb,
    float* __restrict__ DIN, unsigned short* __restrict__ Hbf,
    float* __restrict__ Ab, float* __restrict__ rel_out) {

    __shared__ unsigned short gf[6 * 64 * 8];    // gates A-frags, 6KB
    __shared__ unsigned short a2f[5 * 64 * 8];   // Ab A-frags, 5KB
    __shared__ float hsh[16 * HD];               // h_lstm, 8KB
    __shared__ float relsh[16][4];

    int gsc = blockIdx.x;          // scene
    int t = threadIdx.x;
    int lane = t & 63, w = t >> 6;
    int colid = lane & 15, quad = lane >> 4;

    // build gates A-frags: [din(64) | h_prev(128)], K=192 = 6 kt
    if (t < 384) {
        int kt = t >> 6;
        int j = lane & 15;
        int b = gsc * PP + j;
        int k0 = kt * 32 + ((lane >> 4) << 3);
        float4 x0, x1;
        if (k0 < ED) {
            const float4* p = (const float4*)(DIN + b * ED + k0);
            x0 = p[0]; x1 = p[1];
        } else {
            const float4* p = (const float4*)(Hb + b * HD + (k0 - ED));
            x0 = p[0]; x1 = p[1];
        }
        bf16x8 o;
        o[0] = f2bf(x0.x); o[1] = f2bf(x0.y); o[2] = f2bf(x0.z); o[3] = f2bf(x0.w);
        o[4] = f2bf(x1.x); o[5] = f2bf(x1.y); o[6] = f2bf(x1.z); o[7] = f2bf(x1.w);
        *(bf16x8*)(gf + t * 8) = o;
    }
    __syncthreads();

    // gates MFMA
    f32x4 acc[4];
#pragma unroll
    for (int gi = 0; gi < 4; ++gi) acc[gi] = (f32x4)0.f;
#pragma unroll
    for (int kt = 0; kt < 6; ++kt) {
        bf16x8 af = *(const bf16x8*)(gf + (kt * 64 + lane) * 8);
#pragma unroll
        for (int gi = 0; gi < 4; ++gi) {
            bf16x8 bfr = *(const bf16x8*)(WcatF + ((kt * 32 + gi * 8 + w) * 64 + lane) * 8);
            acc[gi] = __builtin_amdgcn_mfma_f32_16x16x32_bf16(af, bfr, acc[gi], 0, 0, 0);
        }
    }
    // LSTM cell, all four gates in-wave
    int hcol = w * 16 + colid;
    float bias[4];
#pragma unroll
    for (int gi = 0; gi < 4; ++gi) {
        int n = (gi * 8 + w) * 16 + colid;
        bias[gi] = b_ih[n] + b_hh[n];
    }
#pragma unroll
    for (int r = 0; r < 4; ++r) {
        int row = quad * 4 + r;
        int b = gsc * PP + row;
        float gI = acc[0][r] + bias[0];
        float gF = acc[1][r] + bias[1];
        float gG = acc[2][r] + bias[2];
        float gO = acc[3][r] + bias[3];
        float c = Cb[b * HD + hcol];
        float cn = (1.f / (1.f + expf(-gF))) * c + (1.f / (1.f + expf(-gI))) * tanhf(gG);
        float hn = (1.f / (1.f + expf(-gO))) * tanhf(cn);
        Cb[b * HD + hcol] = cn;
        Hbf[b * HD + hcol] = (unsigned short)f2bf(hn);
        hsh[row * HD + hcol] = hn;
    }
    __syncthreads();

    // rel_pos: 32 threads per row, shuffle reduce
    {
        int row = t >> 5, kk = t & 31;
        float r0 = 0.f, r1 = 0.f;
#pragma unroll
        for (int q = 0; q < 4; ++q) {
            int k = kk + q * 32;
            float hv = hsh[row * HD + k];
            r0 = fmaf(hv, W_pos[k], r0);
            r1 = fmaf(hv, W_pos[HD + k], r1);
        }
#pragma unroll
        for (int m = 16; m >= 1; m >>= 1) {
            r0 += __shfl_xor(r0, m, 64);
            r1 += __shfl_xor(r1, m, 64);
        }
        if (kk == 0) {
            int b = gsc * PP + row;
            r0 += b_pos[0]; r1 += b_pos[1];
            float px = POSb[b * 2 + 0] + r0;
            float py = POSb[b * 2 + 1] + r1;
            POSb[b * 2 + 0] = px; POSb[b * 2 + 1] = py;
            rel_out[b * 2 + 0] = r0; rel_out[b * 2 + 1] = r1;
            relsh[row][0] = r0; relsh[row][1] = r1; relsh[row][2] = px; relsh[row][3] = py;
        }
    }
    __syncthreads();

    // next dec_in
#pragma unroll
    for (int rep = 0; rep < 2; ++rep) {
        int idx = rep * 512 + t;
        int row = idx >> 6, e = idx & 63;
        int b = gsc * PP + row;
        DIN[b * ED + e] = W_emb[e * 2 + 0] * relsh[row][0] +
                          W_emb[e * 2 + 1] * relsh[row][1] + b_emb[e];
    }
    // Ab A-frags: [h(128) | px | py | 1 | 0pad], K=160 = 5 kt
    if (t < 320) {
        int kt = t >> 6;
        int j = lane & 15;
        int k0 = kt * 32 + ((lane >> 4) << 3);
        bf16x8 o;
#pragma unroll
        for (int e = 0; e < 8; ++e) {
            int k = k0 + e;
            float v;
            if (k < HD)            v = hsh[j * HD + k];
            else if (k == HD)      v = relsh[j][2];
            else if (k == HD + 1)  v = relsh[j][3];
            else if (k == HD + 2)  v = 1.f;
            else                   v = 0.f;
            o[e] = f2bf(v);
        }
        *(bf16x8*)(a2f + t * 8) = o;
    }
    __syncthreads();

    // Ab MFMA: wave w -> nt = w*4+q (512 cols total)
    f32x4 acc2[4];
#pragma unroll
    for (int q = 0; q < 4; ++q) acc2[q] = (f32x4)0.f;
#pragma unroll
    for (int kt = 0; kt < 5; ++kt) {
        bf16x8 af = *(const bf16x8*)(a2f + (kt * 64 + lane) * 8);
#pragma unroll
        for (int q = 0; q < 4; ++q) {
            bf16x8 bfr = *(const bf16x8*)(Wp1F2 + ((kt * 32 + w * 4 + q) * 64 + lane) * 8);
            acc2[q] = __builtin_amdgcn_mfma_f32_16x16x32_bf16(af, bfr, acc2[q], 0, 0, 0);
        }
    }
#pragma unroll
    for (int q = 0; q < 4; ++q)
#pragma unroll
        for (int r = 0; r < 4; ++r) {
            int b = gsc * PP + quad * 4 + r;
            Ab[b * MIDD + (w * 4 + q) * 16 + colid] = acc2[q][r];
        }
}

// ---------------------------------------------------------------------------
// build_y1: materialize Y1[i][j][k] = relu(a_j[k] - s_i[k]) ONCE per step,
// in MFMA A-fragment order, bf16, to global (25MB; XCD-L2 resident).
// grid = B = 1536 blocks (one per (g,i)), 256 thr. Zero replication.
// Y1F unit (gi*16 + kt)*64 + l holds A[j=l&15][k=kt*32+((l>>4)<<3)+e].
// ---------------------------------------------------------------------------
__global__ __launch_bounds__(256) void build_y1_kernel(
    const float* __restrict__ Ab, const float* __restrict__ POSb,
    const float* __restrict__ M0, const float* __restrict__ M1,
    unsigned short* __restrict__ Y1F) {

    __shared__ __align__(16) float s_lds[MIDD];

    int bi = blockIdx.x;
    int g = bi % 96;                 // scene -> XCD-local (96 % 8 == 0)
    int i = bi / 96;                 // 0..15
    int gi = g * PP + i;
    int t = threadIdx.x;

    float px = POSb[gi * 2 + 0], py = POSb[gi * 2 + 1];
    s_lds[t]       = fmaf(M0[t], px, M1[t] * py);
    s_lds[t + 256] = fmaf(M0[t + 256], px, M1[t + 256] * py);
    __syncthreads();

    const float* Ag = Ab + g * (PP * MIDD);
    unsigned short* dst = Y1F + (size_t)gi * (16 * 64 * 8);
#pragma unroll
    for (int rep = 0; rep < 4; ++rep) {
        int u = rep * 256 + t;           // 0..1023 units
        int kt = u >> 6, l = u & 63;
        int j = l & 15;
        int k0 = kt * 32 + ((l >> 4) << 3);
        const float4* ap = (const float4*)(Ag + j * MIDD + k0);
        float4 a0 = ap[0], a1 = ap[1];
        const float4* sp = (const float4*)(s_lds + k0);
        float4 s0 = sp[0], s1 = sp[1];
        bf16x8 o;
        o[0] = f2bf(fmaxf(a0.x - s0.x, 0.f));
        o[1] = f2bf(fmaxf(a0.y - s0.y, 0.f));
        o[2] = f2bf(fmaxf(a0.z - s0.z, 0.f));
        o[3] = f2bf(fmaxf(a0.w - s0.w, 0.f));
        o[4] = f2bf(fmaxf(a1.x - s1.x, 0.f));
        o[5] = f2bf(fmaxf(a1.y - s1.y, 0.f));
        o[6] = f2bf(fmaxf(a1.z - s1.z, 0.f));
        o[7] = f2bf(fmaxf(a1.w - s1.w, 0.f));
        *(bf16x8*)(dst + u * 8) = o;
    }
}

// ---------------------------------------------------------------------------
// pool_gemm6: pure MFMA GEMM, no LDS, no barriers. A (Y1F) and B (Wp2F)
// streamed from XCD-local L2 as coalesced 16B fragment loads.
// grid = 96*2*8 = 1536 blocks, 256 thr (4 waves). Block: (g, io octet, colq
// of 8 nt). Wave w: i-pair io*8 + w*2 + {0,1}, all 8 nt. acc = 2x8x4 = 64.
// Epilogue: max over C rows (j) + cross-quad shuffles.
// ---------------------------------------------------------------------------
__global__ __launch_bounds__(256, 3) void pool_gemm6_kernel(
    const unsigned short* __restrict__ Y1F,
    const unsigned short* __restrict__ Wp2F, const float* __restrict__ bp2,
    unsigned short* __restrict__ POOLbf) {

    int bi = blockIdx.x;
    int g = bi % 96;                 // scene -> XCD-local
    int rest = bi / 96;              // 0..15
    int io = rest >> 3;              // 0..1
    int colq = rest & 7;             // 0..7
    int t = threadIdx.x, lane = t & 63, w = t >> 6;

    int i0 = io * 8 + w * 2;         // first i of this wave's pair
    const unsigned short* a0p = Y1F + ((size_t)(g * PP + i0) * 16) * 512;
    const unsigned short* a1p = a0p + 16 * 512;
    int ntb = colq * 8;

    f32x4 acc[2][8];
#pragma unroll
    for (int p = 0; p < 2; ++p)
#pragma unroll
        for (int n = 0; n < 8; ++n) acc[p][n] = (f32x4)0.f;

#pragma unroll
    for (int kt = 0; kt < 16; ++kt) {
        bf16x8 af0 = *(const bf16x8*)(a0p + (kt * 64 + lane) * 8);
        bf16x8 af1 = *(const bf16x8*)(a1p + (kt * 64 + lane) * 8);
#pragma unroll
        for (int ng = 0; ng < 2; ++ng) {
            bf16x8 bfr[4];
#pragma unroll
            for (int n = 0; n < 4; ++n)
                bfr[n] = *(const bf16x8*)(Wp2F + ((kt * 64 + ntb + ng * 4 + n) * 64 + lane) * 8);
#pragma unroll
            for (int n = 0; n < 4; ++n) {
                acc[0][ng * 4 + n] =
                    __builtin_amdgcn_mfma_f32_16x16x32_bf16(af0, bfr[n], acc[0][ng * 4 + n], 0, 0, 0);
                acc[1][ng * 4 + n] =
                    __builtin_amdgcn_mfma_f32_16x16x32_bf16(af1, bfr[n], acc[1][ng * 4 + n], 0, 0, 0);
            }
        }
    }

    int quad = lane >> 4, colid = lane & 15;
#pragma unroll
    for (int p = 0; p < 2; ++p) {
        int i = g * PP + i0 + p;
#pragma unroll
        for (int n = 0; n < 8; ++n) {
            float m = fmaxf(fmaxf(acc[p][n][0], acc[p][n][1]),
                            fmaxf(acc[p][n][2], acc[p][n][3]));
            m = fmaxf(m, __shfl_xor(m, 16, 64));
            m = fmaxf(m, __shfl_xor(m, 32, 64));
            if (quad == 0) {
                int col = (ntb + n) * 16 + colid;
                float v = fmaxf(m + bp2[col], 0.f);
                POOLbf[i * BOT + col] = (unsigned short)f2bf(v);
            }
        }
    }
}

// ---------------------------------------------------------------------------
// MLP1 (MFMA): [Hbf | POOLbf] (1536x1152) @ Wm1F -> relu -> Y1Mbf (1536x1024)
// ---------------------------------------------------------------------------
__global__ __launch_bounds__(256) void mlp1_mfma_kernel(
    const unsigned short* __restrict__ Hbf, const unsigned short* __restrict__ POOLbf,
    const unsigned short* __restrict__ Wm1F, const float* __restrict__ bm1,
    unsigned short* __restrict__ Y1Mbf) {

    __shared__ unsigned short a_f[16 * 64 * 8];   // 16KB
    int mg = blockIdx.x;       // 0..23
    int ng = blockIdx.y;       // 0..15
    int t = threadIdx.x, lane = t & 63, w = t >> 6;
    int rh = w >> 1, nh = w & 1;

    f32x4 acc[2][2];
#pragma unroll
    for (int a = 0; a < 2; ++a)
#pragma unroll
        for (int b = 0; b < 2; ++b) acc[a][b] = (f32x4)0.f;

    for (int c = 0; c < 9; ++c) {
        __syncthreads();
#pragma unroll
        for (int u0 = 0; u0 < 1024; u0 += 256) {
            int u = u0 + t;
            int rg = u >> 8, kt = (u >> 6) & 3, l = u & 63;
            int row = mg * 64 + rg * 16 + (l & 15);
            int kl = kt * 32 + ((l >> 4) << 3);
            const unsigned short* src = (c == 0) ? (Hbf + row * HD + kl)
                                                 : (POOLbf + row * BOT + (c - 1) * 128 + kl);
            *(bf16x8*)(a_f + u * 8) = *(const bf16x8*)src;
        }
        __syncthreads();
#pragma unroll
        for (int kt = 0; kt < 4; ++kt) {
            int ktg = c * 4 + kt;
            bf16x8 bfr[2];
#pragma unroll
            for (int j = 0; j < 2; ++j) {
                int ntg = ng * 4 + nh * 2 + j;
                bfr[j] = *(const bf16x8*)(Wm1F + ((ktg * 64 + ntg) * 64 + lane) * 8);
            }
#pragma unroll
            for (int ri = 0; ri < 2; ++ri) {
                int rg = rh * 2 + ri;
                bf16x8 af = *(const bf16x8*)(a_f + ((rg * 4 + kt) * 64 + lane) * 8);
#pragma unroll
                for (int j = 0; j < 2; ++j)
                    acc[ri][j] = __builtin_amdgcn_mfma_f32_16x16x32_bf16(af, bfr[j], acc[ri][j], 0, 0, 0);
            }
        }
    }
    int quad = lane >> 4, colid = lane & 15;
#pragma unroll
    for (int ri = 0; ri < 2; ++ri)
#pragma unroll
        for (int j = 0; j < 2; ++j) {
            int col = ng * 64 + (nh * 2 + j) * 16 + colid;
            float bb = bm1[col];
#pragma unroll
            for (int r = 0; r < 4; ++r) {
                int row = mg * 64 + (rh * 2 + ri) * 16 + quad * 4 + r;
                float v = fmaxf(acc[ri][j][r] + bb, 0.f);
                Y1Mbf[row * MLPH + col] = (unsigned short)f2bf(v);
            }
        }
}

// ---------------------------------------------------------------------------
// MLP2 (MFMA): Y1Mbf (1536x1024) @ Wm2F -> relu -> Hb fp32 (and h_out last step)
// ---------------------------------------------------------------------------
__global__ __launch_bounds__(256) void mlp2_mfma_kernel(
    const unsigned short* __restrict__ Y1Mbf, const unsigned short* __restrict__ Wm2F,
    const float* __restrict__ bm2, float* __restrict__ Hb, float* __restrict__ hout) {

    __shared__ unsigned short a_f[32 * 64 * 8];   // 32KB
    int rg = blockIdx.x;   // 0..95
    int t = threadIdx.x, lane = t & 63, w = t >> 6;

#pragma unroll
    for (int u0 = 0; u0 < 2048; u0 += 256) {
        int u = u0 + t;
        int kt = u >> 6, l = u & 63;
        int row = rg * 16 + (l & 15);
        int kl = kt * 32 + ((l >> 4) << 3);
        *(bf16x8*)(a_f + u * 8) = *(const bf16x8*)(Y1Mbf + row * MLPH + kl);
    }
    __syncthreads();

    f32x4 acc[2];
    acc[0] = (f32x4)0.f; acc[1] = (f32x4)0.f;
    for (int kt = 0; kt < 32; ++kt) {
        bf16x8 af = *(const bf16x8*)(a_f + (kt * 64 + lane) * 8);
#pragma unroll
        for (int j = 0; j < 2; ++j) {
            int ntg = w * 2 + j;
            bf16x8 bfr = *(const bf16x8*)(Wm2F + ((kt * 8 + ntg) * 64 + lane) * 8);
            acc[j] = __builtin_amdgcn_mfma_f32_16x16x32_bf16(af, bfr, acc[j], 0, 0, 0);
        }
    }
    int quad = lane >> 4, colid = lane & 15;
#pragma unroll
    for (int j = 0; j < 2; ++j) {
        int col = (w * 2 + j) * 16 + colid;
        float bb = bm2[col];
#pragma unroll
        for (int r = 0; r < 4; ++r) {
            int row = rg * 16 + quad * 4 + r;
            float v = fmaxf(acc[j][r] + bb, 0.f);
            Hb[row * HD + col] = v;
            if (hout) hout[row * HD + col] = v;
        }
    }
}

// ---------------------------------------------------------------------------
extern "C" void kernel_launch(void* const* d_in, const int* in_sizes, int n_in,
                              void* d_out, int out_size, void* d_ws, size_t ws_size,
                              hipStream_t stream) {
    const float* obs_traj     = (const float*)d_in[0];
    const float* obs_traj_rel = (const float*)d_in[1];
    const float* h0    = (const float*)d_in[3];
    const float* c0    = (const float*)d_in[4];
    const float* W_emb = (const float*)d_in[6];
    const float* b_emb = (const float*)d_in[7];
    const float* W_ih  = (const float*)d_in[8];
    const float* b_ih  = (const float*)d_in[9];
    const float* W_hh  = (const float*)d_in[10];
    const float* b_hh  = (const float*)d_in[11];
    const float* W_pos = (const float*)d_in[12];
    const float* b_pos = (const float*)d_in[13];
    const float* Wp_emb= (const float*)d_in[14];
    const float* bp_emb= (const float*)d_in[15];
    const float* Wp1   = (const float*)d_in[16];
    const float* bp1   = (const float*)d_in[17];
    const float* Wp2   = (const float*)d_in[18];
    const float* bp2   = (const float*)d_in[19];
    const float* Wm1   = (const float*)d_in[20];
    const float* bm1   = (const float*)d_in[21];
    const float* Wm2   = (const float*)d_in[22];
    const float* bm2   = (const float*)d_in[23];

    float* ws = (float*)d_ws;
    float* Hb    = ws; ws += B * HD;
    float* Cb    = ws; ws += B * HD;
    float* POSb  = ws; ws += B * 2;
    float* DIN   = ws; ws += B * ED;
    float* Ab    = ws; ws += B * MIDD;
    float* M0    = ws; ws += MIDD;
    float* M1    = ws; ws += MIDD;
    float* CV    = ws; ws += MIDD;
    unsigned short* us = (unsigned short*)ws;
    unsigned short* Hbf    = us; us += B * HD;
    unsigned short* POOLbf = us; us += B * BOT;
    unsigned short* Y1Mbf  = us; us += B * MLPH;
    unsigned short* WcatF  = us; us += 6 * 32 * 64 * 8;
    unsigned short* Wp1F2  = us; us += 5 * 32 * 64 * 8;
    unsigned short* Wp2F   = us; us += MIDD * BOT;
    unsigned short* Wm1F   = us; us += CTXD * MLPH;
    unsigned short* Wm2F   = us; us += MLPH * HD;
    unsigned short* Y1F    = us; us += (size_t)B * 16 * 64 * 8;   // 25MB frag-order Y1

    float* out = (float*)d_out;
    float* rels_out = out;                 // (12,1536,2)
    float* h_out    = out + SEQL * B * 2;  // (1536,128)

    // setup
    {
        int tot = 16 * 64 * 64;   // Wp2: K=512, NT=64
        swizzleB_kernel<<<(tot + 255) / 256, 256, 0, stream>>>(Wp2, Wp2F, 64, MIDD, tot);
        tot = 36 * 64 * 64;       // Wm1: K=1152, NT=64
        swizzleB_kernel<<<(tot + 255) / 256, 256, 0, stream>>>(Wm1, Wm1F, 64, CTXD, tot);
        tot = 32 * 8 * 64;        // Wm2: K=1024, NT=8
        swizzleB_kernel<<<(tot + 255) / 256, 256, 0, stream>>>(Wm2, Wm2F, 8, MLPH, tot);
        swizzle_cat_kernel<<<(6 * 32 * 64 + 255) / 256, 256, 0, stream>>>(W_ih, W_hh, WcatF);
    }
    mcvec_kernel<<<2, 256, 0, stream>>>(Wp1, Wp_emb, bp_emb, bp1, M0, M1, CV);
    swizzle_p1_kernel<<<(5 * 32 * 64 + 255) / 256, 256, 0, stream>>>(Wp1, M0, M1, CV, Wp1F2);
    init_kernel<<<B, 128, 0, stream>>>(obs_traj, obs_traj_rel, h0, c0, W_emb, b_emb,
                                       Hb, Cb, POSb, DIN);

    for (int s = 0; s < SEQL; ++s) {
        step_kernel<<<G, 512, 0, stream>>>(
            WcatF, b_ih, b_hh, W_pos, b_pos, W_emb, b_emb, Wp1F2,
            Hb, Cb, POSb, DIN, Hbf, Ab, rels_out + s * B * 2);
        build_y1_kernel<<<B, 256, 0, stream>>>(Ab, POSb, M0, M1, Y1F);
        pool_gemm6_kernel<<<G * 16, 256, 0, stream>>>(Y1F, Wp2F, bp2, POOLbf);
        mlp1_mfma_kernel<<<dim3(24, 16), 256, 0, stream>>>(Hbf, POOLbf, Wm1F, bm1, Y1Mbf);
        mlp2_mfma_kernel<<<G, 256, 0, stream>>>(Y1Mbf, Wm2F, bm2, Hb,
                                                (s == SEQL - 1) ? h_out : (float*)nullptr);
    }
}

// Round 9
// 1164.443 us; speedup vs baseline: 1.4975x; 1.0179x over previous
//
#include <hip/hip_runtime.h>
#include <math.h>

#define OBS 8
#define SEQL 12
#define G 96
#define PP 16
#define B 1536
#define HD 128
#define ED 64
#define BOT 1024
#define MIDD 512
#define CTXD (HD + BOT)   /* 1152 */
#define MLPH 1024

typedef __attribute__((ext_vector_type(8))) short bf16x8;
typedef __attribute__((ext_vector_type(4))) float f32x4;

__device__ inline short f2bf(float x) {
    union { float f; unsigned u; } v; v.f = x;
    unsigned r = v.u + 0x7fffu + ((v.u >> 16) & 1u);   // RNE
    return (short)(r >> 16);
}

// ---------------------------------------------------------------------------
// setup kernels
// ---------------------------------------------------------------------------
// B-matrix -> MFMA-fragment-order bf16. src is (Nrows x Kcols) row-major fp32.
// dst unit u = (kt*NT + nt)*64 + lane: B[n=nt*16+(l&15)][k=kt*32+((l>>4)<<3)+e]
__global__ void swizzleB_kernel(const float* __restrict__ src, unsigned short* __restrict__ dst,
                                int NT, int K, int total) {
    int u = blockIdx.x * 256 + threadIdx.x;
    if (u >= total) return;
    int l = u & 63; int v = u >> 6; int nt = v % NT; int kt = v / NT;
    int n = nt * 16 + (l & 15);
    int k = kt * 32 + ((l >> 4) << 3);
    const float* s = src + n * K + k;
    float4 s0 = *(const float4*)s;
    float4 s1 = *(const float4*)(s + 4);
    bf16x8 o;
    o[0] = f2bf(s0.x); o[1] = f2bf(s0.y); o[2] = f2bf(s0.z); o[3] = f2bf(s0.w);
    o[4] = f2bf(s1.x); o[5] = f2bf(s1.y); o[6] = f2bf(s1.z); o[7] = f2bf(s1.w);
    *(bf16x8*)(dst + u * 8) = o;
}

// gates B = [W_ih | W_hh] (512 x 192) -> frag order (6 kt x 32 nt)
__global__ void swizzle_cat_kernel(const float* __restrict__ W_ih, const float* __restrict__ W_hh,
                                   unsigned short* __restrict__ dst) {
    int u = blockIdx.x * 256 + threadIdx.x;   // 6*32*64 = 12288 units
    if (u >= 6 * 32 * 64) return;
    int l = u & 63; int v = u >> 6; int nt = v & 31; int kt = v >> 5;
    int n = nt * 16 + (l & 15);
    int k0 = kt * 32 + ((l >> 4) << 3);
    bf16x8 o;
#pragma unroll
    for (int e = 0; e < 8; ++e) {
        int k = k0 + e;
        float val = (k < ED) ? W_ih[n * ED + k] : W_hh[n * HD + (k - ED)];
        o[e] = f2bf(val);
    }
    *(bf16x8*)(dst + u * 8) = o;
}

// u B-matrix = [Wp1_h | 0 | 0 | CV | 0pad] (512 x 160) -> frag order (5 kt x 32 nt)
// (M0/M1 position rows removed — pool adds M*(pj-pi) in exact fp32)
__global__ void swizzle_p1_kernel(const float* __restrict__ Wp1,
                                  const float* __restrict__ CV,
                                  unsigned short* __restrict__ dst) {
    int u = blockIdx.x * 256 + threadIdx.x;   // 5*32*64 = 10240 units
    if (u >= 5 * 32 * 64) return;
    int l = u & 63; int v = u >> 6; int nt = v & 31; int kt = v >> 5;
    int n = nt * 16 + (l & 15);
    int k0 = kt * 32 + ((l >> 4) << 3);
    bf16x8 o;
#pragma unroll
    for (int e = 0; e < 8; ++e) {
        int k = k0 + e;
        float val;
        if (k < HD)           val = Wp1[n * (ED + HD) + ED + k];
        else if (k == HD + 2) val = CV[n];
        else                  val = 0.f;
        o[e] = f2bf(val);
    }
    *(bf16x8*)(dst + u * 8) = o;
}

// M = Wp1[:, :64] @ Wp_emb  (512x2), cvec = Wp1[:, :64] @ bp_emb + bp1
__global__ void mcvec_kernel(const float* __restrict__ Wp1, const float* __restrict__ Wp_emb,
                             const float* __restrict__ bp_emb, const float* __restrict__ bp1,
                             float* __restrict__ M0, float* __restrict__ M1, float* __restrict__ CV) {
    int r = blockIdx.x * blockDim.x + threadIdx.x;
    if (r >= MIDD) return;
    float m0 = 0.f, m1 = 0.f, cv = 0.f;
    for (int e = 0; e < ED; ++e) {
        float w = Wp1[r * (ED + HD) + e];
        m0 += w * Wp_emb[e * 2 + 0];
        m1 += w * Wp_emb[e * 2 + 1];
        cv += w * bp_emb[e];
    }
    M0[r] = m0; M1[r] = m1; CV[r] = cv + bp1[r];
}

// frag-order fp32 M tables: M0F[(kt*64+lane)*8+e] = M0[kt*32+(lane>>4)*8+e]
__global__ void m01f_kernel(const float* __restrict__ M0, const float* __restrict__ M1,
                            float* __restrict__ M0F, float* __restrict__ M1F) {
    int id = blockIdx.x * 256 + threadIdx.x;   // 16*64*8 = 8192
    if (id >= 16 * 64 * 8) return;
    int e = id & 7;
    int lane = (id >> 3) & 63;
    int kt = id >> 9;
    int k = kt * 32 + ((lane >> 4) << 3) + e;
    M0F[id] = M0[k];
    M1F[id] = M1[k];
}

__global__ void init_kernel(const float* __restrict__ obs_traj, const float* __restrict__ obs_traj_rel,
                            const float* __restrict__ h0, const float* __restrict__ c0,
                            const float* __restrict__ W_emb, const float* __restrict__ b_emb,
                            float* __restrict__ Hb, float* __restrict__ Cb,
                            float* __restrict__ POSb, float* __restrict__ DIN) {
    int b = blockIdx.x;
    int t = threadIdx.x; // 128
    Hb[b * HD + t] = h0[b * HD + t];
    Cb[b * HD + t] = c0[b * HD + t];
    if (t < 2) POSb[b * 2 + t] = obs_traj[((OBS - 1) * B + b) * 2 + t];
    if (t < ED) {
        float rx = obs_traj_rel[((OBS - 1) * B + b) * 2 + 0];
        float ry = obs_traj_rel[((OBS - 1) * B + b) * 2 + 1];
        DIN[b * ED + t] = W_emb[t * 2 + 0] * rx + W_emb[t * 2 + 1] * ry + b_emb[t];
    }
}

// ---------------------------------------------------------------------------
// fused step: gates MFMA -> LSTM cell (in-reg) -> rel_pos -> POS/DIN update ->
// u MFMA (u = Wp1h*h + CV, position-free). Block = one scene, 512 thr.
// Writes AbF (u) in MFMA A-fragment order (fp32).
// ---------------------------------------------------------------------------
__global__ __launch_bounds__(512) void step_kernel(
    const unsigned short* __restrict__ WcatF, const float* __restrict__ b_ih,
    const float* __restrict__ b_hh,
    const float* __restrict__ W_pos, const float* __restrict__ b_pos,
    const float* __restrict__ W_emb, const float* __restrict__ b_emb,
    const unsigned short* __restrict__ Wp1F2,
    float* __restrict__ Hb, float* __restrict__ Cb, float* __restrict__ POSb,
    float* __restrict__ DIN, unsigned short* __restrict__ Hbf,
    float* __restrict__ AbF, float* __restrict__ rel_out) {

    __shared__ unsigned short gf[6 * 64 * 8];    // gates A-frags, 6KB
    __shared__ unsigned short a2f[5 * 64 * 8];   // u A-frags, 5KB
    __shared__ float hsh[16 * HD];               // h_lstm, 8KB
    __shared__ float relsh[16][4];

    int gsc = blockIdx.x;          // scene
    int t = threadIdx.x;
    int lane = t & 63, w = t >> 6;
    int colid = lane & 15, quad = lane >> 4;

    // build gates A-frags: [din(64) | h_prev(128)], K=192 = 6 kt
    if (t < 384) {
        int kt = t >> 6;
        int j = lane & 15;
        int b = gsc * PP + j;
        int k0 = kt * 32 + ((lane >> 4) << 3);
        float4 x0, x1;
        if (k0 < ED) {
            const float4* p = (const float4*)(DIN + b * ED + k0);
            x0 = p[0]; x1 = p[1];
        } else {
            const float4* p = (const float4*)(Hb + b * HD + (k0 - ED));
            x0 = p[0]; x1 = p[1];
        }
        bf16x8 o;
        o[0] = f2bf(x0.x); o[1] = f2bf(x0.y); o[2] = f2bf(x0.z); o[3] = f2bf(x0.w);
        o[4] = f2bf(x1.x); o[5] = f2bf(x1.y); o[6] = f2bf(x1.z); o[7] = f2bf(x1.w);
        *(bf16x8*)(gf + t * 8) = o;
    }
    __syncthreads();

    // gates MFMA
    f32x4 acc[4];
#pragma unroll
    for (int gi = 0; gi < 4; ++gi) acc[gi] = (f32x4)0.f;
#pragma unroll
    for (int kt = 0; kt < 6; ++kt) {
        bf16x8 af = *(const bf16x8*)(gf + (kt * 64 + lane) * 8);
#pragma unroll
        for (int gi = 0; gi < 4; ++gi) {
            bf16x8 bfr = *(const bf16x8*)(WcatF + ((kt * 32 + gi * 8 + w) * 64 + lane) * 8);
            acc[gi] = __builtin_amdgcn_mfma_f32_16x16x32_bf16(af, bfr, acc[gi], 0, 0, 0);
        }
    }
    // LSTM cell, all four gates in-wave
    int hcol = w * 16 + colid;
    float bias[4];
#pragma unroll
    for (int gi = 0; gi < 4; ++gi) {
        int n = (gi * 8 + w) * 16 + colid;
        bias[gi] = b_ih[n] + b_hh[n];
    }
#pragma unroll
    for (int r = 0; r < 4; ++r) {
        int row = quad * 4 + r;
        int b = gsc * PP + row;
        float gI = acc[0][r] + bias[0];
        float gF = acc[1][r] + bias[1];
        float gG = acc[2][r] + bias[2];
        float gO = acc[3][r] + bias[3];
        float c = Cb[b * HD + hcol];
        float cn = (1.f / (1.f + expf(-gF))) * c + (1.f / (1.f + expf(-gI))) * tanhf(gG);
        float hn = (1.f / (1.f + expf(-gO))) * tanhf(cn);
        Cb[b * HD + hcol] = cn;
        Hbf[b * HD + hcol] = (unsigned short)f2bf(hn);
        hsh[row * HD + hcol] = hn;
    }
    __syncthreads();

    // rel_pos: 32 threads per row, shuffle reduce
    {
        int row = t >> 5, kk = t & 31;
        float r0 = 0.f, r1 = 0.f;
#pragma unroll
        for (int q = 0; q < 4; ++q) {
            int k = kk + q * 32;
            float hv = hsh[row * HD + k];
            r0 = fmaf(hv, W_pos[k], r0);
            r1 = fmaf(hv, W_pos[HD + k], r1);
        }
#pragma unroll
        for (int m = 16; m >= 1; m >>= 1) {
            r0 += __shfl_xor(r0, m, 64);
            r1 += __shfl_xor(r1, m, 64);
        }
        if (kk == 0) {
            int b = gsc * PP + row;
            r0 += b_pos[0]; r1 += b_pos[1];
            float px = POSb[b * 2 + 0] + r0;
            float py = POSb[b * 2 + 1] + r1;
            POSb[b * 2 + 0] = px; POSb[b * 2 + 1] = py;
            rel_out[b * 2 + 0] = r0; rel_out[b * 2 + 1] = r1;
            relsh[row][0] = r0; relsh[row][1] = r1; relsh[row][2] = px; relsh[row][3] = py;
        }
    }
    __syncthreads();

    // next dec_in
#pragma unroll
    for (int rep = 0; rep < 2; ++rep) {
        int idx = rep * 512 + t;
        int row = idx >> 6, e = idx & 63;
        int b = gsc * PP + row;
        DIN[b * ED + e] = W_emb[e * 2 + 0] * relsh[row][0] +
                          W_emb[e * 2 + 1] * relsh[row][1] + b_emb[e];
    }
    // u A-frags: [h(128) | 0 | 0 | 1 | 0pad], K=160 = 5 kt
    if (t < 320) {
        int kt = t >> 6;
        int j = lane & 15;
        int k0 = kt * 32 + ((lane >> 4) << 3);
        bf16x8 o;
#pragma unroll
        for (int e = 0; e < 8; ++e) {
            int k = k0 + e;
            float v;
            if (k < HD)            v = hsh[j * HD + k];
            else if (k == HD + 2)  v = 1.f;
            else                   v = 0.f;
            o[e] = f2bf(v);
        }
        *(bf16x8*)(a2f + t * 8) = o;
    }
    __syncthreads();

    // u MFMA: wave w -> nt = w*4+q (512 cols total); write AbF in frag order
    f32x4 acc2[4];
#pragma unroll
    for (int q = 0; q < 4; ++q) acc2[q] = (f32x4)0.f;
#pragma unroll
    for (int kt = 0; kt < 5; ++kt) {
        bf16x8 af = *(const bf16x8*)(a2f + (kt * 64 + lane) * 8);
#pragma unroll
        for (int q = 0; q < 4; ++q) {
            bf16x8 bfr = *(const bf16x8*)(Wp1F2 + ((kt * 32 + w * 4 + q) * 64 + lane) * 8);
            acc2[q] = __builtin_amdgcn_mfma_f32_16x16x32_bf16(af, bfr, acc2[q], 0, 0, 0);
        }
    }
#pragma unroll
    for (int q = 0; q < 4; ++q)
#pragma unroll
        for (int r = 0; r < 4; ++r) {
            int j = quad * 4 + r;                 // row within scene
            int k = (w * 4 + q) * 16 + colid;     // col (k-dim of pool GEMM)
            int kt2 = k >> 5, lk = (k >> 3) & 3, e = k & 7;
            AbF[((gsc * 16 + kt2) * 64 + lk * 16 + j) * 8 + e] = acc2[q][r];
        }
}

// ---------------------------------------------------------------------------
// pool_gemm8: LDS-free, barrier-free MFMA GEMM with exact fp32 position terms.
// rel[k] = u_j[k] + M0[k]*(pxj-pxi) + M1[k]*(pyj-pyi); af = f2bf(relu(rel)).
// grid = 96*2*8 = 1536 blocks, 256 thr (4 waves). Block: (g, io octet, colq).
// Wave w: i-pair io*8+w*2+{0,1}, 8 nt. All data via coalesced L2 loads.
// ---------------------------------------------------------------------------
__global__ __launch_bounds__(256, 4) void pool_gemm8_kernel(
    const float* __restrict__ AbF, const float* __restrict__ POSb,
    const float* __restrict__ M0F, const float* __restrict__ M1F,
    const unsigned short* __restrict__ Wp2F, const float* __restrict__ bp2,
    unsigned short* __restrict__ POOLbf) {

    int bi = blockIdx.x;
    int g = bi % 96;                 // scene -> XCD-local
    int rest = bi / 96;              // 0..15
    int io = rest >> 3;              // 0..1
    int colq = rest & 7;             // 0..7
    int t = threadIdx.x, lane = t & 63, w = t >> 6;
    int i0 = io * 8 + w * 2;
    int j = lane & 15;

    float pjx = POSb[(g * PP + j) * 2 + 0];
    float pjy = POSb[(g * PP + j) * 2 + 1];
    float dx[2], dy[2];
#pragma unroll
    for (int p = 0; p < 2; ++p) {
        int gi = g * PP + i0 + p;
        dx[p] = pjx - POSb[gi * 2 + 0];
        dy[p] = pjy - POSb[gi * 2 + 1];
    }

    int ntb = colq * 8;
    f32x4 acc[2][8];
#pragma unroll
    for (int p = 0; p < 2; ++p)
#pragma unroll
        for (int n = 0; n < 8; ++n) acc[p][n] = (f32x4)0.f;

    const float* ag = AbF + (size_t)g * (16 * 64 * 8);

#pragma unroll
    for (int kt = 0; kt < 16; ++kt) {
        int off = (kt * 64 + lane) * 8;
        const float4* up = (const float4*)(ag + off);
        float4 u0 = up[0], u1 = up[1];
        const float4* m0p = (const float4*)(M0F + off);
        float4 m00 = m0p[0], m01 = m0p[1];
        const float4* m1p = (const float4*)(M1F + off);
        float4 m10 = m1p[0], m11 = m1p[1];
        bf16x8 af[2];
#pragma unroll
        for (int p = 0; p < 2; ++p) {
            float dxp = dx[p], dyp = dy[p];
            af[p][0] = f2bf(fmaxf(fmaf(m10.x, dyp, fmaf(m00.x, dxp, u0.x)), 0.f));
            af[p][1] = f2bf(fmaxf(fmaf(m10.y, dyp, fmaf(m00.y, dxp, u0.y)), 0.f));
            af[p][2] = f2bf(fmaxf(fmaf(m10.z, dyp, fmaf(m00.z, dxp, u0.z)), 0.f));
            af[p][3] = f2bf(fmaxf(fmaf(m10.w, dyp, fmaf(m00.w, dxp, u0.w)), 0.f));
            af[p][4] = f2bf(fmaxf(fmaf(m11.x, dyp, fmaf(m01.x, dxp, u1.x)), 0.f));
            af[p][5] = f2bf(fmaxf(fmaf(m11.y, dyp, fmaf(m01.y, dxp, u1.y)), 0.f));
            af[p][6] = f2bf(fmaxf(fmaf(m11.z, dyp, fmaf(m01.z, dxp, u1.z)), 0.f));
            af[p][7] = f2bf(fmaxf(fmaf(m11.w, dyp, fmaf(m01.w, dxp, u1.w)), 0.f));
        }
#pragma unroll
        for (int ng = 0; ng < 2; ++ng) {
            bf16x8 bfr[4];
#pragma unroll
            for (int n = 0; n < 4; ++n)
                bfr[n] = *(const bf16x8*)(Wp2F + ((kt * 64 + ntb + ng * 4 + n) * 64 + lane) * 8);
#pragma unroll
            for (int n = 0; n < 4; ++n) {
                acc[0][ng * 4 + n] =
                    __builtin_amdgcn_mfma_f32_16x16x32_bf16(af[0], bfr[n], acc[0][ng * 4 + n], 0, 0, 0);
                acc[1][ng * 4 + n] =
                    __builtin_amdgcn_mfma_f32_16x16x32_bf16(af[1], bfr[n], acc[1][ng * 4 + n], 0, 0, 0);
            }
        }
    }

    int quad = lane >> 4, colid = lane & 15;
#pragma unroll
    for (int p = 0; p < 2; ++p) {
        int i = g * PP + i0 + p;
#pragma unroll
        for (int n = 0; n < 8; ++n) {
            float m = fmaxf(fmaxf(acc[p][n][0], acc[p][n][1]),
                            fmaxf(acc[p][n][2], acc[p][n][3]));
            m = fmaxf(m, __shfl_xor(m, 16, 64));
            m = fmaxf(m, __shfl_xor(m, 32, 64));
            if (quad == 0) {
                int col = (ntb + n) * 16 + colid;
                float v = fmaxf(m + bp2[col], 0.f);
                POOLbf[i * BOT + col] = (unsigned short)f2bf(v);
            }
        }
    }
}

// ---------------------------------------------------------------------------
// MLP1 (MFMA): [Hbf | POOLbf] (1536x1152) @ Wm1F -> relu -> Y1Mbf (1536x1024)
// ---------------------------------------------------------------------------
__global__ __launch_bounds__(256) void mlp1_mfma_kernel(
    const unsigned short* __restrict__ Hbf, const unsigned short* __restrict__ POOLbf,
    const unsigned short* __restrict__ Wm1F, const float* __restrict__ bm1,
    unsigned short* __restrict__ Y1Mbf) {

    __shared__ unsigned short a_f[16 * 64 * 8];   // 16KB
    int mg = blockIdx.x;       // 0..23
    int ng = blockIdx.y;       // 0..15
    int t = threadIdx.x, lane = t & 63, w = t >> 6;
    int rh = w >> 1, nh = w & 1;

    f32x4 acc[2][2];
#pragma unroll
    for (int a = 0; a < 2; ++a)
#pragma unroll
        for (int b = 0; b < 2; ++b) acc[a][b] = (f32x4)0.f;

    for (int c = 0; c < 9; ++c) {
        __syncthreads();
#pragma unroll
        for (int u0 = 0; u0 < 1024; u0 += 256) {
            int u = u0 + t;
            int rg = u >> 8, kt = (u >> 6) & 3, l = u & 63;
            int row = mg * 64 + rg * 16 + (l & 15);
            int kl = kt * 32 + ((l >> 4) << 3);
            const unsigned short* src = (c == 0) ? (Hbf + row * HD + kl)
                                                 : (POOLbf + row * BOT + (c - 1) * 128 + kl);
            *(bf16x8*)(a_f + u * 8) = *(const bf16x8*)src;
        }
        __syncthreads();
#pragma unroll
        for (int kt = 0; kt < 4; ++kt) {
            int ktg = c * 4 + kt;
            bf16x8 bfr[2];
#pragma unroll
            for (int j = 0; j < 2; ++j) {
                int ntg = ng * 4 + nh * 2 + j;
                bfr[j] = *(const bf16x8*)(Wm1F + ((ktg * 64 + ntg) * 64 + lane) * 8);
            }
#pragma unroll
            for (int ri = 0; ri < 2; ++ri) {
                int rg = rh * 2 + ri;
                bf16x8 af = *(const bf16x8*)(a_f + ((rg * 4 + kt) * 64 + lane) * 8);
#pragma unroll
                for (int j = 0; j < 2; ++j)
                    acc[ri][j] = __builtin_amdgcn_mfma_f32_16x16x32_bf16(af, bfr[j], acc[ri][j], 0, 0, 0);
            }
        }
    }
    int quad = lane >> 4, colid = lane & 15;
#pragma unroll
    for (int ri = 0; ri < 2; ++ri)
#pragma unroll
        for (int j = 0; j < 2; ++j) {
            int col = ng * 64 + (nh * 2 + j) * 16 + colid;
            float bb = bm1[col];
#pragma unroll
            for (int r = 0; r < 4; ++r) {
                int row = mg * 64 + (rh * 2 + ri) * 16 + quad * 4 + r;
                float v = fmaxf(acc[ri][j][r] + bb, 0.f);
                Y1Mbf[row * MLPH + col] = (unsigned short)f2bf(v);
            }
        }
}

// ---------------------------------------------------------------------------
// MLP2 (MFMA): Y1Mbf (1536x1024) @ Wm2F -> relu -> Hb fp32 (and h_out last step)
// ---------------------------------------------------------------------------
__global__ __launch_bounds__(256) void mlp2_mfma_kernel(
    const unsigned short* __restrict__ Y1Mbf, const unsigned short* __restrict__ Wm2F,
    const float* __restrict__ bm2, float* __restrict__ Hb, float* __restrict__ hout) {

    __shared__ unsigned short a_f[32 * 64 * 8];   // 32KB
    int rg = blockIdx.x;   // 0..95
    int t = threadIdx.x, lane = t & 63, w = t >> 6;

#pragma unroll
    for (int u0 = 0; u0 < 2048; u0 += 256) {
        int u = u0 + t;
        int kt = u >> 6, l = u & 63;
        int row = rg * 16 + (l & 15);
        int kl = kt * 32 + ((l >> 4) << 3);
        *(bf16x8*)(a_f + u * 8) = *(const bf16x8*)(Y1Mbf + row * MLPH + kl);
    }
    __syncthreads();

    f32x4 acc[2];
    acc[0] = (f32x4)0.f; acc[1] = (f32x4)0.f;
    for (int kt = 0; kt < 32; ++kt) {
        bf16x8 af = *(const bf16x8*)(a_f + (kt * 64 + lane) * 8);
#pragma unroll
        for (int j = 0; j < 2; ++j) {
            int ntg = w * 2 + j;
            bf16x8 bfr = *(const bf16x8*)(Wm2F + ((kt * 8 + ntg) * 64 + lane) * 8);
            acc[j] = __builtin_amdgcn_mfma_f32_16x16x32_bf16(af, bfr, acc[j], 0, 0, 0);
        }
    }
    int quad = lane >> 4, colid = lane & 15;
#pragma unroll
    for (int j = 0; j < 2; ++j) {
        int col = (w * 2 + j) * 16 + colid;
        float bb = bm2[col];
#pragma unroll
        for (int r = 0; r < 4; ++r) {
            int row = rg * 16 + quad * 4 + r;
            float v = fmaxf(acc[j][r] + bb, 0.f);
            Hb[row * HD + col] = v;
            if (hout) hout[row * HD + col] = v;
        }
    }
}

// ---------------------------------------------------------------------------
extern "C" void kernel_launch(void* const* d_in, const int* in_sizes, int n_in,
                              void* d_out, int out_size, void* d_ws, size_t ws_size,
                              hipStream_t stream) {
    const float* obs_traj     = (const float*)d_in[0];
    const float* obs_traj_rel = (const float*)d_in[1];
    const float* h0    = (const float*)d_in[3];
    const float* c0    = (const float*)d_in[4];
    const float* W_emb = (const float*)d_in[6];
    const float* b_emb = (const float*)d_in[7];
    const float* W_ih  = (const float*)d_in[8];
    const float* b_ih  = (const float*)d_in[9];
    const float* W_hh  = (const float*)d_in[10];
    const float* b_hh  = (const float*)d_in[11];
    const float* W_pos = (const float*)d_in[12];
    const float* b_pos = (const float*)d_in[13];
    const float* Wp_emb= (const float*)d_in[14];
    const float* bp_emb= (const float*)d_in[15];
    const float* Wp1   = (const float*)d_in[16];
    const float* bp1   = (const float*)d_in[17];
    const float* Wp2   = (const float*)d_in[18];
    const float* bp2   = (const float*)d_in[19];
    const float* Wm1   = (const float*)d_in[20];
    const float* bm1   = (const float*)d_in[21];
    const float* Wm2   = (const float*)d_in[22];
    const float* bm2   = (const float*)d_in[23];

    float* ws = (float*)d_ws;
    float* Hb    = ws; ws += B * HD;
    float* Cb    = ws; ws += B * HD;
    float* POSb  = ws; ws += B * 2;
    float* DIN   = ws; ws += B * ED;
    float* AbF   = ws; ws += B * MIDD;   // frag-order u (96 scenes x 16kt x 64 x 8)
    float* M0    = ws; ws += MIDD;
    float* M1    = ws; ws += MIDD;
    float* CV    = ws; ws += MIDD;
    float* M0F   = ws; ws += 16 * 64 * 8;
    float* M1F   = ws; ws += 16 * 64 * 8;
    unsigned short* us = (unsigned short*)ws;
    unsigned short* Hbf    = us; us += B * HD;
    unsigned short* POOLbf = us; us += B * BOT;
    unsigned short* Y1Mbf  = us; us += B * MLPH;
    unsigned short* WcatF  = us; us += 6 * 32 * 64 * 8;
    unsigned short* Wp1F2  = us; us += 5 * 32 * 64 * 8;
    unsigned short* Wp2F   = us; us += MIDD * BOT;
    unsigned short* Wm1F   = us; us += CTXD * MLPH;
    unsigned short* Wm2F   = us; us += MLPH * HD;

    float* out = (float*)d_out;
    float* rels_out = out;                 // (12,1536,2)
    float* h_out    = out + SEQL * B * 2;  // (1536,128)

    // setup
    {
        int tot = 16 * 64 * 64;   // Wp2: K=512, NT=64
        swizzleB_kernel<<<(tot + 255) / 256, 256, 0, stream>>>(Wp2, Wp2F, 64, MIDD, tot);
        tot = 36 * 64 * 64;       // Wm1: K=1152, NT=64
        swizzleB_kernel<<<(tot + 255) / 256, 256, 0, stream>>>(Wm1, Wm1F, 64, CTXD, tot);
        tot = 32 * 8 * 64;        // Wm2: K=1024, NT=8
        swizzleB_kernel<<<(tot + 255) / 256, 256, 0, stream>>>(Wm2, Wm2F, 8, MLPH, tot);
        swizzle_cat_kernel<<<(6 * 32 * 64 + 255) / 256, 256, 0, stream>>>(W_ih, W_hh, WcatF);
    }
    mcvec_kernel<<<2, 256, 0, stream>>>(Wp1, Wp_emb, bp_emb, bp1, M0, M1, CV);
    swizzle_p1_kernel<<<(5 * 32 * 64 + 255) / 256, 256, 0, stream>>>(Wp1, CV, Wp1F2);
    m01f_kernel<<<32, 256, 0, stream>>>(M0, M1, M0F, M1F);
    init_kernel<<<B, 128, 0, stream>>>(obs_traj, obs_traj_rel, h0, c0, W_emb, b_emb,
                                       Hb, Cb, POSb, DIN);

    for (int s = 0; s < SEQL; ++s) {
        step_kernel<<<G, 512, 0, stream>>>(
            WcatF, b_ih, b_hh, W_pos, b_pos, W_emb, b_emb, Wp1F2,
            Hb, Cb, POSb, DIN, Hbf, AbF, rels_out + s * B * 2);
        pool_gemm8_kernel<<<G * 16, 256, 0, stream>>>(AbF, POSb, M0F, M1F, Wp2F, bp2, POOLbf);
        mlp1_mfma_kernel<<<dim3(24, 16), 256, 0, stream>>>(Hbf, POOLbf, Wm1F, bm1, Y1Mbf);
        mlp2_mfma_kernel<<<G, 256, 0, stream>>>(Y1Mbf, Wm2F, bm2, Hb,
                                                (s == SEQL - 1) ? h_out : (float*)nullptr);
    }
}

// Round 10
// 1083.208 us; speedup vs baseline: 1.6098x; 1.0750x over previous
//
#include <hip/hip_runtime.h>
#include <math.h>

#define OBS 8
#define SEQL 12
#define G 96
#define PP 16
#define B 1536
#define HD 128
#define ED 64
#define BOT 1024
#define MIDD 512
#define CTXD (HD + BOT)   /* 1152 */
#define MLPH 1024

typedef __attribute__((ext_vector_type(8))) short bf16x8;
typedef __attribute__((ext_vector_type(4))) float f32x4;

__device__ inline short f2bf(float x) {
    union { float f; unsigned u; } v; v.f = x;
    unsigned r = v.u + 0x7fffu + ((v.u >> 16) & 1u);   // RNE
    return (short)(r >> 16);
}

// ---------------------------------------------------------------------------
// setup kernels
// ---------------------------------------------------------------------------
// B-matrix -> MFMA-fragment-order bf16. src is (Nrows x Kcols) row-major fp32.
// dst unit u = (kt*NT + nt)*64 + lane: B[n=nt*16+(l&15)][k=kt*32+((l>>4)<<3)+e]
__global__ void swizzleB_kernel(const float* __restrict__ src, unsigned short* __restrict__ dst,
                                int NT, int K, int total) {
    int u = blockIdx.x * 256 + threadIdx.x;
    if (u >= total) return;
    int l = u & 63; int v = u >> 6; int nt = v % NT; int kt = v / NT;
    int n = nt * 16 + (l & 15);
    int k = kt * 32 + ((l >> 4) << 3);
    const float* s = src + n * K + k;
    float4 s0 = *(const float4*)s;
    float4 s1 = *(const float4*)(s + 4);
    bf16x8 o;
    o[0] = f2bf(s0.x); o[1] = f2bf(s0.y); o[2] = f2bf(s0.z); o[3] = f2bf(s0.w);
    o[4] = f2bf(s1.x); o[5] = f2bf(s1.y); o[6] = f2bf(s1.z); o[7] = f2bf(s1.w);
    *(bf16x8*)(dst + u * 8) = o;
}

// gates B = [W_ih | W_hh] (512 x 192) -> frag order (6 kt x 32 nt)
__global__ void swizzle_cat_kernel(const float* __restrict__ W_ih, const float* __restrict__ W_hh,
                                   unsigned short* __restrict__ dst) {
    int u = blockIdx.x * 256 + threadIdx.x;   // 6*32*64 = 12288 units
    if (u >= 6 * 32 * 64) return;
    int l = u & 63; int v = u >> 6; int nt = v & 31; int kt = v >> 5;
    int n = nt * 16 + (l & 15);
    int k0 = kt * 32 + ((l >> 4) << 3);
    bf16x8 o;
#pragma unroll
    for (int e = 0; e < 8; ++e) {
        int k = k0 + e;
        float val = (k < ED) ? W_ih[n * ED + k] : W_hh[n * HD + (k - ED)];
        o[e] = f2bf(val);
    }
    *(bf16x8*)(dst + u * 8) = o;
}

// u B-matrix = [Wp1_h | 0 | 0 | CV | 0pad] (512 x 160) -> frag order (5 kt x 32 nt)
__global__ void swizzle_p1_kernel(const float* __restrict__ Wp1,
                                  const float* __restrict__ CV,
                                  unsigned short* __restrict__ dst) {
    int u = blockIdx.x * 256 + threadIdx.x;   // 5*32*64 = 10240 units
    if (u >= 5 * 32 * 64) return;
    int l = u & 63; int v = u >> 6; int nt = v & 31; int kt = v >> 5;
    int n = nt * 16 + (l & 15);
    int k0 = kt * 32 + ((l >> 4) << 3);
    bf16x8 o;
#pragma unroll
    for (int e = 0; e < 8; ++e) {
        int k = k0 + e;
        float val;
        if (k < HD)           val = Wp1[n * (ED + HD) + ED + k];
        else if (k == HD + 2) val = CV[n];
        else                  val = 0.f;
        o[e] = f2bf(val);
    }
    *(bf16x8*)(dst + u * 8) = o;
}

// M = Wp1[:, :64] @ Wp_emb  (512x2), cvec = Wp1[:, :64] @ bp_emb + bp1
__global__ void mcvec_kernel(const float* __restrict__ Wp1, const float* __restrict__ Wp_emb,
                             const float* __restrict__ bp_emb, const float* __restrict__ bp1,
                             float* __restrict__ M0, float* __restrict__ M1, float* __restrict__ CV) {
    int r = blockIdx.x * blockDim.x + threadIdx.x;
    if (r >= MIDD) return;
    float m0 = 0.f, m1 = 0.f, cv = 0.f;
    for (int e = 0; e < ED; ++e) {
        float w = Wp1[r * (ED + HD) + e];
        m0 += w * Wp_emb[e * 2 + 0];
        m1 += w * Wp_emb[e * 2 + 1];
        cv += w * bp_emb[e];
    }
    M0[r] = m0; M1[r] = m1; CV[r] = cv + bp1[r];
}

// frag-order fp32 M tables: M0F[(kt*64+lane)*8+e] = M0[kt*32+(lane>>4)*8+e]
__global__ void m01f_kernel(const float* __restrict__ M0, const float* __restrict__ M1,
                            float* __restrict__ M0F, float* __restrict__ M1F) {
    int id = blockIdx.x * 256 + threadIdx.x;   // 16*64*8 = 8192
    if (id >= 16 * 64 * 8) return;
    int e = id & 7;
    int lane = (id >> 3) & 63;
    int kt = id >> 9;
    int k = kt * 32 + ((lane >> 4) << 3) + e;
    M0F[id] = M0[k];
    M1F[id] = M1[k];
}

__global__ void init_kernel(const float* __restrict__ obs_traj, const float* __restrict__ obs_traj_rel,
                            const float* __restrict__ h0, const float* __restrict__ c0,
                            const float* __restrict__ W_emb, const float* __restrict__ b_emb,
                            float* __restrict__ Hb, float* __restrict__ Cb,
                            float* __restrict__ POSb, float* __restrict__ DIN) {
    int b = blockIdx.x;
    int t = threadIdx.x; // 128
    Hb[b * HD + t] = h0[b * HD + t];
    Cb[b * HD + t] = c0[b * HD + t];
    if (t < 2) POSb[b * 2 + t] = obs_traj[((OBS - 1) * B + b) * 2 + t];
    if (t < ED) {
        float rx = obs_traj_rel[((OBS - 1) * B + b) * 2 + 0];
        float ry = obs_traj_rel[((OBS - 1) * B + b) * 2 + 1];
        DIN[b * ED + t] = W_emb[t * 2 + 0] * rx + W_emb[t * 2 + 1] * ry + b_emb[t];
    }
}

// ---------------------------------------------------------------------------
// fused step: gates MFMA -> LSTM cell (in-reg) -> rel_pos -> POS/DIN update ->
// u MFMA (u = Wp1h*h + CV, position-free). Block = one scene, 512 thr.
// Writes AbF (u) in MFMA A-fragment order (fp32).
// ---------------------------------------------------------------------------
__global__ __launch_bounds__(512) void step_kernel(
    const unsigned short* __restrict__ WcatF, const float* __restrict__ b_ih,
    const float* __restrict__ b_hh,
    const float* __restrict__ W_pos, const float* __restrict__ b_pos,
    const float* __restrict__ W_emb, const float* __restrict__ b_emb,
    const unsigned short* __restrict__ Wp1F2,
    float* __restrict__ Hb, float* __restrict__ Cb, float* __restrict__ POSb,
    float* __restrict__ DIN, unsigned short* __restrict__ Hbf,
    float* __restrict__ AbF, float* __restrict__ rel_out) {

    __shared__ unsigned short gf[6 * 64 * 8];    // gates A-frags, 6KB
    __shared__ unsigned short a2f[5 * 64 * 8];   // u A-frags, 5KB
    __shared__ float hsh[16 * HD];               // h_lstm, 8KB
    __shared__ float relsh[16][4];

    int gsc = blockIdx.x;          // scene
    int t = threadIdx.x;
    int lane = t & 63, w = t >> 6;
    int colid = lane & 15, quad = lane >> 4;

    // build gates A-frags: [din(64) | h_prev(128)], K=192 = 6 kt
    if (t < 384) {
        int kt = t >> 6;
        int j = lane & 15;
        int b = gsc * PP + j;
        int k0 = kt * 32 + ((lane >> 4) << 3);
        float4 x0, x1;
        if (k0 < ED) {
            const float4* p = (const float4*)(DIN + b * ED + k0);
            x0 = p[0]; x1 = p[1];
        } else {
            const float4* p = (const float4*)(Hb + b * HD + (k0 - ED));
            x0 = p[0]; x1 = p[1];
        }
        bf16x8 o;
        o[0] = f2bf(x0.x); o[1] = f2bf(x0.y); o[2] = f2bf(x0.z); o[3] = f2bf(x0.w);
        o[4] = f2bf(x1.x); o[5] = f2bf(x1.y); o[6] = f2bf(x1.z); o[7] = f2bf(x1.w);
        *(bf16x8*)(gf + t * 8) = o;
    }
    __syncthreads();

    // gates MFMA
    f32x4 acc[4];
#pragma unroll
    for (int gi = 0; gi < 4; ++gi) acc[gi] = (f32x4)0.f;
#pragma unroll
    for (int kt = 0; kt < 6; ++kt) {
        bf16x8 af = *(const bf16x8*)(gf + (kt * 64 + lane) * 8);
#pragma unroll
        for (int gi = 0; gi < 4; ++gi) {
            bf16x8 bfr = *(const bf16x8*)(WcatF + ((kt * 32 + gi * 8 + w) * 64 + lane) * 8);
            acc[gi] = __builtin_amdgcn_mfma_f32_16x16x32_bf16(af, bfr, acc[gi], 0, 0, 0);
        }
    }
    // LSTM cell, all four gates in-wave
    int hcol = w * 16 + colid;
    float bias[4];
#pragma unroll
    for (int gi = 0; gi < 4; ++gi) {
        int n = (gi * 8 + w) * 16 + colid;
        bias[gi] = b_ih[n] + b_hh[n];
    }
#pragma unroll
    for (int r = 0; r < 4; ++r) {
        int row = quad * 4 + r;
        int b = gsc * PP + row;
        float gI = acc[0][r] + bias[0];
        float gF = acc[1][r] + bias[1];
        float gG = acc[2][r] + bias[2];
        float gO = acc[3][r] + bias[3];
        float c = Cb[b * HD + hcol];
        float cn = (1.f / (1.f + expf(-gF))) * c + (1.f / (1.f + expf(-gI))) * tanhf(gG);
        float hn = (1.f / (1.f + expf(-gO))) * tanhf(cn);
        Cb[b * HD + hcol] = cn;
        Hbf[b * HD + hcol] = (unsigned short)f2bf(hn);
        hsh[row * HD + hcol] = hn;
    }
    __syncthreads();

    // rel_pos: 32 threads per row, shuffle reduce
    {
        int row = t >> 5, kk = t & 31;
        float r0 = 0.f, r1 = 0.f;
#pragma unroll
        for (int q = 0; q < 4; ++q) {
            int k = kk + q * 32;
            float hv = hsh[row * HD + k];
            r0 = fmaf(hv, W_pos[k], r0);
            r1 = fmaf(hv, W_pos[HD + k], r1);
        }
#pragma unroll
        for (int m = 16; m >= 1; m >>= 1) {
            r0 += __shfl_xor(r0, m, 64);
            r1 += __shfl_xor(r1, m, 64);
        }
        if (kk == 0) {
            int b = gsc * PP + row;
            r0 += b_pos[0]; r1 += b_pos[1];
            float px = POSb[b * 2 + 0] + r0;
            float py = POSb[b * 2 + 1] + r1;
            POSb[b * 2 + 0] = px; POSb[b * 2 + 1] = py;
            rel_out[b * 2 + 0] = r0; rel_out[b * 2 + 1] = r1;
            relsh[row][0] = r0; relsh[row][1] = r1; relsh[row][2] = px; relsh[row][3] = py;
        }
    }
    __syncthreads();

    // next dec_in
#pragma unroll
    for (int rep = 0; rep < 2; ++rep) {
        int idx = rep * 512 + t;
        int row = idx >> 6, e = idx & 63;
        int b = gsc * PP + row;
        DIN[b * ED + e] = W_emb[e * 2 + 0] * relsh[row][0] +
                          W_emb[e * 2 + 1] * relsh[row][1] + b_emb[e];
    }
    // u A-frags: [h(128) | 0 | 0 | 1 | 0pad], K=160 = 5 kt
    if (t < 320) {
        int kt = t >> 6;
        int j = lane & 15;
        int k0 = kt * 32 + ((lane >> 4) << 3);
        bf16x8 o;
#pragma unroll
        for (int e = 0; e < 8; ++e) {
            int k = k0 + e;
            float v;
            if (k < HD)            v = hsh[j * HD + k];
            else if (k == HD + 2)  v = 1.f;
            else                   v = 0.f;
            o[e] = f2bf(v);
        }
        *(bf16x8*)(a2f + t * 8) = o;
    }
    __syncthreads();

    // u MFMA: wave w -> nt = w*4+q (512 cols total); write AbF in frag order
    f32x4 acc2[4];
#pragma unroll
    for (int q = 0; q < 4; ++q) acc2[q] = (f32x4)0.f;
#pragma unroll
    for (int kt = 0; kt < 5; ++kt) {
        bf16x8 af = *(const bf16x8*)(a2f + (kt * 64 + lane) * 8);
#pragma unroll
        for (int q = 0; q < 4; ++q) {
            bf16x8 bfr = *(const bf16x8*)(Wp1F2 + ((kt * 32 + w * 4 + q) * 64 + lane) * 8);
            acc2[q] = __builtin_amdgcn_mfma_f32_16x16x32_bf16(af, bfr, acc2[q], 0, 0, 0);
        }
    }
#pragma unroll
    for (int q = 0; q < 4; ++q)
#pragma unroll
        for (int r = 0; r < 4; ++r) {
            int j = quad * 4 + r;                 // row within scene
            int k = (w * 4 + q) * 16 + colid;     // col (k-dim of pool GEMM)
            int kt2 = k >> 5, lk = (k >> 3) & 3, e = k & 7;
            AbF[((gsc * 16 + kt2) * 64 + lk * 16 + j) * 8 + e] = acc2[q][r];
        }
}

// ---------------------------------------------------------------------------
// pool_gemm9: same decomposition/math as gemm8, but per-kt streams (B, u,
// M0F, M1F) staged into double-buffered LDS once per block and shared by all
// 4 waves — cuts L2 read traffic 4x (the measured 40µs floor of gemm8).
// grid = 1536 (g, io, colq), 256 thr. Build af in regs with exact fp32
// position terms; 16 MFMA/kt/wave; max epilogue.
// ---------------------------------------------------------------------------
__global__ __launch_bounds__(256, 3) void pool_gemm9_kernel(
    const float* __restrict__ AbF, const float* __restrict__ POSb,
    const float* __restrict__ M0F, const float* __restrict__ M1F,
    const unsigned short* __restrict__ Wp2F, const float* __restrict__ bp2,
    unsigned short* __restrict__ POOLbf) {

    __shared__ __align__(16) unsigned short Bst[2][8 * 64 * 8];   // 2 x 8KB
    __shared__ __align__(16) float Ust[2][64 * 8];                // 2 x 2KB
    __shared__ __align__(16) float M0st[2][64 * 8];               // 2 x 2KB
    __shared__ __align__(16) float M1st[2][64 * 8];               // 2 x 2KB

    int bi = blockIdx.x;
    int g = bi % 96;                 // scene -> XCD-local
    int rest = bi / 96;              // 0..15
    int io = rest >> 3;              // 0..1
    int colq = rest & 7;             // 0..7
    int t = threadIdx.x, lane = t & 63, w = t >> 6;
    int i0 = io * 8 + w * 2;
    int j = lane & 15;
    int ntb = colq * 8;

    float pjx = POSb[(g * PP + j) * 2 + 0];
    float pjy = POSb[(g * PP + j) * 2 + 1];
    float dx[2], dy[2];
#pragma unroll
    for (int p = 0; p < 2; ++p) {
        int gi = g * PP + i0 + p;
        dx[p] = pjx - POSb[gi * 2 + 0];
        dy[p] = pjy - POSb[gi * 2 + 1];
    }

    const float* ag = AbF + (size_t)g * (16 * 64 * 8);

    // stage streams for k-tile kt into buffer buf (all 256 threads)
    auto stage = [&](int kt, int buf) {
        // B: 8 nt x 64 lanes x 16B = 512 units, 2 per thread
#pragma unroll
        for (int r = 0; r < 2; ++r) {
            int u = r * 256 + t;            // 0..511
            int nt = u >> 6, l = u & 63;
            *(bf16x8*)&Bst[buf][u * 8] =
                *(const bf16x8*)(Wp2F + ((kt * 64 + ntb + nt) * 64 + l) * 8);
        }
        // u / M0 / M1: 128 float4-units each
        if (t < 128) {
            *(float4*)&Ust[buf][t * 4] = *(const float4*)(ag + kt * 512 + t * 4);
            *(float4*)&M1st[buf][t * 4] = *(const float4*)(M1F + kt * 512 + t * 4);
        } else {
            int q = t - 128;
            *(float4*)&M0st[buf][q * 4] = *(const float4*)(M0F + kt * 512 + q * 4);
        }
    };

    f32x4 acc[2][8];
#pragma unroll
    for (int p = 0; p < 2; ++p)
#pragma unroll
        for (int n = 0; n < 8; ++n) acc[p][n] = (f32x4)0.f;

    stage(0, 0);
    __syncthreads();

    for (int kt = 0; kt < 16; ++kt) {
        int buf = kt & 1;
        if (kt < 15) stage(kt + 1, buf ^ 1);

        const float4* up = (const float4*)&Ust[buf][lane * 8];
        float4 u0 = up[0], u1 = up[1];
        const float4* m0p = (const float4*)&M0st[buf][lane * 8];
        float4 m00 = m0p[0], m01 = m0p[1];
        const float4* m1p = (const float4*)&M1st[buf][lane * 8];
        float4 m10 = m1p[0], m11 = m1p[1];

        bf16x8 af[2];
#pragma unroll
        for (int p = 0; p < 2; ++p) {
            float dxp = dx[p], dyp = dy[p];
            af[p][0] = f2bf(fmaxf(fmaf(m10.x, dyp, fmaf(m00.x, dxp, u0.x)), 0.f));
            af[p][1] = f2bf(fmaxf(fmaf(m10.y, dyp, fmaf(m00.y, dxp, u0.y)), 0.f));
            af[p][2] = f2bf(fmaxf(fmaf(m10.z, dyp, fmaf(m00.z, dxp, u0.z)), 0.f));
            af[p][3] = f2bf(fmaxf(fmaf(m10.w, dyp, fmaf(m00.w, dxp, u0.w)), 0.f));
            af[p][4] = f2bf(fmaxf(fmaf(m11.x, dyp, fmaf(m01.x, dxp, u1.x)), 0.f));
            af[p][5] = f2bf(fmaxf(fmaf(m11.y, dyp, fmaf(m01.y, dxp, u1.y)), 0.f));
            af[p][6] = f2bf(fmaxf(fmaf(m11.z, dyp, fmaf(m01.z, dxp, u1.z)), 0.f));
            af[p][7] = f2bf(fmaxf(fmaf(m11.w, dyp, fmaf(m01.w, dxp, u1.w)), 0.f));
        }
#pragma unroll
        for (int ng = 0; ng < 2; ++ng) {
            bf16x8 bfr[4];
#pragma unroll
            for (int n = 0; n < 4; ++n)
                bfr[n] = *(const bf16x8*)&Bst[buf][((ng * 4 + n) * 64 + lane) * 8];
#pragma unroll
            for (int n = 0; n < 4; ++n) {
                acc[0][ng * 4 + n] =
                    __builtin_amdgcn_mfma_f32_16x16x32_bf16(af[0], bfr[n], acc[0][ng * 4 + n], 0, 0, 0);
                acc[1][ng * 4 + n] =
                    __builtin_amdgcn_mfma_f32_16x16x32_bf16(af[1], bfr[n], acc[1][ng * 4 + n], 0, 0, 0);
            }
        }
        __syncthreads();   // staging of kt+1 done; reads of buf done
    }

    int quad = lane >> 4, colid = lane & 15;
#pragma unroll
    for (int p = 0; p < 2; ++p) {
        int i = g * PP + i0 + p;
#pragma unroll
        for (int n = 0; n < 8; ++n) {
            float m = fmaxf(fmaxf(acc[p][n][0], acc[p][n][1]),
                            fmaxf(acc[p][n][2], acc[p][n][3]));
            m = fmaxf(m, __shfl_xor(m, 16, 64));
            m = fmaxf(m, __shfl_xor(m, 32, 64));
            if (quad == 0) {
                int col = (ntb + n) * 16 + colid;
                float v = fmaxf(m + bp2[col], 0.f);
                POOLbf[i * BOT + col] = (unsigned short)f2bf(v);
            }
        }
    }
}

// ---------------------------------------------------------------------------
// MLP1 (MFMA): [Hbf | POOLbf] (1536x1152) @ Wm1F -> relu -> Y1Mbf (1536x1024)
// ---------------------------------------------------------------------------
__global__ __launch_bounds__(256) void mlp1_mfma_kernel(
    const unsigned short* __restrict__ Hbf, const unsigned short* __restrict__ POOLbf,
    const unsigned short* __restrict__ Wm1F, const float* __restrict__ bm1,
    unsigned short* __restrict__ Y1Mbf) {

    __shared__ unsigned short a_f[16 * 64 * 8];   // 16KB
    int mg = blockIdx.x;       // 0..23
    int ng = blockIdx.y;       // 0..15
    int t = threadIdx.x, lane = t & 63, w = t >> 6;
    int rh = w >> 1, nh = w & 1;

    f32x4 acc[2][2];
#pragma unroll
    for (int a = 0; a < 2; ++a)
#pragma unroll
        for (int b = 0; b < 2; ++b) acc[a][b] = (f32x4)0.f;

    for (int c = 0; c < 9; ++c) {
        __syncthreads();
#pragma unroll
        for (int u0 = 0; u0 < 1024; u0 += 256) {
            int u = u0 + t;
            int rg = u >> 8, kt = (u >> 6) & 3, l = u & 63;
            int row = mg * 64 + rg * 16 + (l & 15);
            int kl = kt * 32 + ((l >> 4) << 3);
            const unsigned short* src = (c == 0) ? (Hbf + row * HD + kl)
                                                 : (POOLbf + row * BOT + (c - 1) * 128 + kl);
            *(bf16x8*)(a_f + u * 8) = *(const bf16x8*)src;
        }
        __syncthreads();
#pragma unroll
        for (int kt = 0; kt < 4; ++kt) {
            int ktg = c * 4 + kt;
            bf16x8 bfr[2];
#pragma unroll
            for (int j = 0; j < 2; ++j) {
                int ntg = ng * 4 + nh * 2 + j;
                bfr[j] = *(const bf16x8*)(Wm1F + ((ktg * 64 + ntg) * 64 + lane) * 8);
            }
#pragma unroll
            for (int ri = 0; ri < 2; ++ri) {
                int rg = rh * 2 + ri;
                bf16x8 af = *(const bf16x8*)(a_f + ((rg * 4 + kt) * 64 + lane) * 8);
#pragma unroll
                for (int j = 0; j < 2; ++j)
                    acc[ri][j] = __builtin_amdgcn_mfma_f32_16x16x32_bf16(af, bfr[j], acc[ri][j], 0, 0, 0);
            }
        }
    }
    int quad = lane >> 4, colid = lane & 15;
#pragma unroll
    for (int ri = 0; ri < 2; ++ri)
#pragma unroll
        for (int j = 0; j < 2; ++j) {
            int col = ng * 64 + (nh * 2 + j) * 16 + colid;
            float bb = bm1[col];
#pragma unroll
            for (int r = 0; r < 4; ++r) {
                int row = mg * 64 + (rh * 2 + ri) * 16 + quad * 4 + r;
                float v = fmaxf(acc[ri][j][r] + bb, 0.f);
                Y1Mbf[row * MLPH + col] = (unsigned short)f2bf(v);
            }
        }
}

// ---------------------------------------------------------------------------
// MLP2 (MFMA): Y1Mbf (1536x1024) @ Wm2F -> relu -> Hb fp32 (and h_out last step)
// ---------------------------------------------------------------------------
__global__ __launch_bounds__(256) void mlp2_mfma_kernel(
    const unsigned short* __restrict__ Y1Mbf, const unsigned short* __restrict__ Wm2F,
    const float* __restrict__ bm2, float* __restrict__ Hb, float* __restrict__ hout) {

    __shared__ unsigned short a_f[32 * 64 * 8];   // 32KB
    int rg = blockIdx.x;   // 0..95
    int t = threadIdx.x, lane = t & 63, w = t >> 6;

#pragma unroll
    for (int u0 = 0; u0 < 2048; u0 += 256) {
        int u = u0 + t;
        int kt = u >> 6, l = u & 63;
        int row = rg * 16 + (l & 15);
        int kl = kt * 32 + ((l >> 4) << 3);
        *(bf16x8*)(a_f + u * 8) = *(const bf16x8*)(Y1Mbf + row * MLPH + kl);
    }
    __syncthreads();

    f32x4 acc[2];
    acc[0] = (f32x4)0.f; acc[1] = (f32x4)0.f;
    for (int kt = 0; kt < 32; ++kt) {
        bf16x8 af = *(const bf16x8*)(a_f + (kt * 64 + lane) * 8);
#pragma unroll
        for (int j = 0; j < 2; ++j) {
            int ntg = w * 2 + j;
            bf16x8 bfr = *(const bf16x8*)(Wm2F + ((kt * 8 + ntg) * 64 + lane) * 8);
            acc[j] = __builtin_amdgcn_mfma_f32_16x16x32_bf16(af, bfr, acc[j], 0, 0, 0);
        }
    }
    int quad = lane >> 4, colid = lane & 15;
#pragma unroll
    for (int j = 0; j < 2; ++j) {
        int col = (w * 2 + j) * 16 + colid;
        float bb = bm2[col];
#pragma unroll
        for (int r = 0; r < 4; ++r) {
            int row = rg * 16 + quad * 4 + r;
            float v = fmaxf(acc[j][r] + bb, 0.f);
            Hb[row * HD + col] = v;
            if (hout) hout[row * HD + col] = v;
        }
    }
}

// ---------------------------------------------------------------------------
extern "C" void kernel_launch(void* const* d_in, const int* in_sizes, int n_in,
                              void* d_out, int out_size, void* d_ws, size_t ws_size,
                              hipStream_t stream) {
    const float* obs_traj     = (const float*)d_in[0];
    const float* obs_traj_rel = (const float*)d_in[1];
    const float* h0    = (const float*)d_in[3];
    const float* c0    = (const float*)d_in[4];
    const float* W_emb = (const float*)d_in[6];
    const float* b_emb = (const float*)d_in[7];
    const float* W_ih  = (const float*)d_in[8];
    const float* b_ih  = (const float*)d_in[9];
    const float* W_hh  = (const float*)d_in[10];
    const float* b_hh  = (const float*)d_in[11];
    const float* W_pos = (const float*)d_in[12];
    const float* b_pos = (const float*)d_in[13];
    const float* Wp_emb= (const float*)d_in[14];
    const float* bp_emb= (const float*)d_in[15];
    const float* Wp1   = (const float*)d_in[16];
    const float* bp1   = (const float*)d_in[17];
    const float* Wp2   = (const float*)d_in[18];
    const float* bp2   = (const float*)d_in[19];
    const float* Wm1   = (const float*)d_in[20];
    const float* bm1   = (const float*)d_in[21];
    const float* Wm2   = (const float*)d_in[22];
    const float* bm2   = (const float*)d_in[23];

    float* ws = (float*)d_ws;
    float* Hb    = ws; ws += B * HD;
    float* Cb    = ws; ws += B * HD;
    float* POSb  = ws; ws += B * 2;
    float* DIN   = ws; ws += B * ED;
    float* AbF   = ws; ws += B * MIDD;   // frag-order u (96 scenes x 16kt x 64 x 8)
    float* M0    = ws; ws += MIDD;
    float* M1    = ws; ws += MIDD;
    float* CV    = ws; ws += MIDD;
    float* M0F   = ws; ws += 16 * 64 * 8;
    float* M1F   = ws; ws += 16 * 64 * 8;
    unsigned short* us = (unsigned short*)ws;
    unsigned short* Hbf    = us; us += B * HD;
    unsigned short* POOLbf = us; us += B * BOT;
    unsigned short* Y1Mbf  = us; us += B * MLPH;
    unsigned short* WcatF  = us; us += 6 * 32 * 64 * 8;
    unsigned short* Wp1F2  = us; us += 5 * 32 * 64 * 8;
    unsigned short* Wp2F   = us; us += MIDD * BOT;
    unsigned short* Wm1F   = us; us += CTXD * MLPH;
    unsigned short* Wm2F   = us; us += MLPH * HD;

    float* out = (float*)d_out;
    float* rels_out = out;                 // (12,1536,2)
    float* h_out    = out + SEQL * B * 2;  // (1536,128)

    // setup
    {
        int tot = 16 * 64 * 64;   // Wp2: K=512, NT=64
        swizzleB_kernel<<<(tot + 255) / 256, 256, 0, stream>>>(Wp2, Wp2F, 64, MIDD, tot);
        tot = 36 * 64 * 64;       // Wm1: K=1152, NT=64
        swizzleB_kernel<<<(tot + 255) / 256, 256, 0, stream>>>(Wm1, Wm1F, 64, CTXD, tot);
        tot = 32 * 8 * 64;        // Wm2: K=1024, NT=8
        swizzleB_kernel<<<(tot + 255) / 256, 256, 0, stream>>>(Wm2, Wm2F, 8, MLPH, tot);
        swizzle_cat_kernel<<<(6 * 32 * 64 + 255) / 256, 256, 0, stream>>>(W_ih, W_hh, WcatF);
    }
    mcvec_kernel<<<2, 256, 0, stream>>>(Wp1, Wp_emb, bp_emb, bp1, M0, M1, CV);
    swizzle_p1_kernel<<<(5 * 32 * 64 + 255) / 256, 256, 0, stream>>>(Wp1, CV, Wp1F2);
    m01f_kernel<<<32, 256, 0, stream>>>(M0, M1, M0F, M1F);
    init_kernel<<<B, 128, 0, stream>>>(obs_traj, obs_traj_rel, h0, c0, W_emb, b_emb,
                                       Hb, Cb, POSb, DIN);

    for (int s = 0; s < SEQL; ++s) {
        step_kernel<<<G, 512, 0, stream>>>(
            WcatF, b_ih, b_hh, W_pos, b_pos, W_emb, b_emb, Wp1F2,
            Hb, Cb, POSb, DIN, Hbf, AbF, rels_out + s * B * 2);
        pool_gemm9_kernel<<<G * 16, 256, 0, stream>>>(AbF, POSb, M0F, M1F, Wp2F, bp2, POOLbf);
        mlp1_mfma_kernel<<<dim3(24, 16), 256, 0, stream>>>(Hbf, POOLbf, Wm1F, bm1, Y1Mbf);
        mlp2_mfma_kernel<<<G, 256, 0, stream>>>(Y1Mbf, Wm2F, bm2, Hb,
                                                (s == SEQL - 1) ? h_out : (float*)nullptr);
    }
}